// Round 1
// 802.578 us; speedup vs baseline: 1.2090x; 1.2090x over previous
//
#include <hip/hip_runtime.h>
#include <hip/hip_bf16.h>

// ---------------------------------------------------------------------------
// StandardAttention: x -> q,k,v proj -> rope -> causal GQA attention -> o proj
// B=4 T=1024 DM=4096 H=32 KVH=8 HD=128 NREP=4. N = 4096 tokens.
//
// Round 1: GEMMs moved to the 256x256 8-phase schedule (BK=64, 8 waves,
// 128KB dbuf LDS, XOR-swizzled chunks staged via pre-swizzled global src,
// counted vmcnt(6) at K-tile boundaries, setprio around MFMA clusters,
// XCD-aware block swizzle).
//
// Workspace layout (bytes):
//   xb    [4096][4096] bf16   off 0          32MB   (reused for attn out)
//   wqT   [4096][4096] bf16   off 32MB       32MB
//   wkvT  [2048][4096] bf16   off 64MB       16MB
//   woT   [4096][4096] bf16   off 80MB       32MB
//   qh    [4096][4096] bf16   off 112MB      32MB   (q proj, roped+prescaled)
//   kvb   [4096][2048] bf16   off 144MB      16MB   (k|v proj, k roped)
//   vt    [4][8][128][1024] bf16 off 160MB    8MB   (V^T for PV mfma B-frags)
// ---------------------------------------------------------------------------

typedef __hip_bfloat16 bf16;
using frag  = __attribute__((ext_vector_type(8))) short;  // 8 bf16 = 4 VGPR
using facc  = __attribute__((ext_vector_type(4))) float;  // 4 fp32 acc

static __device__ __forceinline__ bf16 f2b(float x) { return __float2bfloat16(x); }

static __device__ __forceinline__ void async_copy16(const void* g, void* l) {
  __builtin_amdgcn_global_load_lds(
      (const __attribute__((address_space(1))) void*)g,
      (__attribute__((address_space(3))) void*)l, 16, 0, 0);
}

static __device__ __forceinline__ facc mfma16(frag a, frag b, facc c) {
  return __builtin_amdgcn_mfma_f32_16x16x32_bf16(a, b, c, 0, 0, 0);
}

#define SBARRIER() do { __builtin_amdgcn_sched_barrier(0); \
                        __builtin_amdgcn_s_barrier(); \
                        __builtin_amdgcn_sched_barrier(0); } while (0)
#define WAIT_LGKM0() do { asm volatile("s_waitcnt lgkmcnt(0)" ::: "memory"); \
                          __builtin_amdgcn_sched_barrier(0); } while (0)
#define WAIT_VM(n) do { asm volatile("s_waitcnt vmcnt(" #n ")" ::: "memory"); \
                        __builtin_amdgcn_sched_barrier(0); } while (0)

// ---------------- conversion kernels ----------------

__global__ void convert_x_kernel(const float* __restrict__ in, bf16* __restrict__ out) {
  int i = (blockIdx.x * blockDim.x + threadIdx.x) * 4;
  float4 v = *(const float4*)(in + i);
  out[i + 0] = f2b(v.x);
  out[i + 1] = f2b(v.y);
  out[i + 2] = f2b(v.z);
  out[i + 3] = f2b(v.w);
}

// in[rows][cols] f32 -> out[cols][rows] bf16. grid (cols/32, rows/32), block (32,8)
__global__ void transpose_conv_kernel(const float* __restrict__ in, bf16* __restrict__ out,
                                      int rows, int cols) {
  __shared__ float tile[32][33];
  int bx = blockIdx.x * 32;
  int by = blockIdx.y * 32;
  int tx = threadIdx.x, ty = threadIdx.y;
#pragma unroll
  for (int i = 0; i < 32; i += 8)
    tile[ty + i][tx] = in[(size_t)(by + ty + i) * cols + bx + tx];
  __syncthreads();
#pragma unroll
  for (int i = 0; i < 32; i += 8)
    out[(size_t)(bx + ty + i) * rows + by + tx] = f2b(tile[tx][ty + i]);
}

// ---------------- 256x256 8-phase GEMM: C[M][N] = A[M][K] * BT[N][K]^T -----
// Tiles: BM=BN=256, BK=64. 512 thr = 8 waves (2M x 4N). Per-wave out 128x64.
// LDS 128KB: A dbuf 2x32KB + B dbuf 2x32KB. Chunk = 16B (8 bf16); a row of
// a tile is 8 chunks (128B); chunk-col is XOR-swizzled with row&7 (bank
// spread for ds_read_b128). global_load_lds needs lane-linear LDS dests, so
// the swizzle permutes the per-lane GLOBAL source chunk instead.
//
// Staged half-tiles (16KB = 2 loads/thread each), aligned with per-wave
// read regions so each dies a phase early:
//   A0 = rows {0-63, 128-191}   (per-wave m-half 0; read P0 only)
//   A1 = rows {64-127, 192-255} (m-half 1; read P2 only)
//   B0 = rows {0-31,64-95,128-159,192-223}   (n-half 0; read P0, held in regs)
//   B1 = complement                           (n-half 1; read P1)
// Phase quadrants: P0=(mh0,nh0) P1=(mh0,nh1) P2=(mh1,nh1) P3=(mh1,nh0).
// Stage slots: P0: A1(t+1)->other buf; P1: B0(t+2); P2: A0(t+2); P3: B1(t+2)
// (t+2 stages into the CURRENT buf's already-dead regions).
// vmcnt(6) at P3 leaves exactly {B0,A0,B1}(t+2) in flight => t+1 fully ready.

template <int KIND>  // 0=A0, 1=A1, 2=B0, 3=B1
static __device__ __forceinline__ void stage_half(const bf16* __restrict__ gsrc,
                                                  char* lds, int Kd, int tid) {
#pragma unroll
  for (int i = 0; i < 2; ++i) {
    int c = i * 512 + tid;
    int chunk;
    if (KIND < 2) chunk = c + ((c >> 9) << 9) + (KIND == 1 ? 512 : 0);
    else          chunk = c + ((c >> 8) << 8) + (KIND == 3 ? 256 : 0);
    int r  = chunk >> 3;
    int gc = (chunk & 7) ^ (r & 7);
    async_copy16(gsrc + (size_t)r * Kd + gc * 8, lds + (size_t)chunk * 16);
  }
}

template <bool OUT_F32>
__global__ __launch_bounds__(512, 2) void gemm256_kernel(
    const bf16* __restrict__ A, const bf16* __restrict__ BT,
    void* __restrict__ Cout, int M, int Nn, int Kd) {
  extern __shared__ char smem[];
  char* As0 = smem;
  char* As1 = smem + 32 * 1024;
  char* Bs0 = smem + 64 * 1024;
  char* Bs1 = smem + 96 * 1024;

  int tid  = threadIdx.x;
  int wave = tid >> 6, lane = tid & 63;
  int ml   = lane & 15, quad = lane >> 4;
  int wm   = wave >> 2, wn = wave & 3;

  // XCD-aware bijective swizzle (grid % 8 == 0 for all our shapes)
  int nbx = Nn >> 8;
  int nwg = gridDim.x;
  int id  = blockIdx.x;
  int swz = (id & 7) * (nwg >> 3) + (id >> 3);
  int bm  = (swz / nbx) << 8;
  int bn  = (swz % nbx) << 8;

  const bf16* Ag = A + (size_t)bm * Kd;
  const bf16* Bg = BT + (size_t)bn * Kd;

  facc acc[8][4];
#pragma unroll
  for (int i = 0; i < 8; ++i)
#pragma unroll
    for (int j = 0; j < 4; ++j)
#pragma unroll
      for (int r = 0; r < 4; ++r) acc[i][j][r] = 0.f;

  auto lda = [&](const char* buf, int mh, int mt, int kk) -> frag {
    int row = wm * 128 + mh * 64 + mt * 16 + ml;        // row&7 == ml&7
    int cs  = (kk * 4 + quad) ^ (ml & 7);
    return *(const frag*)(buf + ((size_t)row * 8 + cs) * 16);
  };
  auto ldb = [&](const char* buf, int nh, int nt, int kk) -> frag {
    int row = wn * 64 + nh * 32 + nt * 16 + ml;         // row&7 == ml&7
    int cs  = (kk * 4 + quad) ^ (ml & 7);
    return *(const frag*)(buf + ((size_t)row * 8 + cs) * 16);
  };

  int NKT = Kd >> 6;

  // prologue: K-tile 0 complete (8 loads) + 3 half-tiles of K-tile 1
  stage_half<0>(Ag,      As0, Kd, tid);
  stage_half<2>(Bg,      Bs0, Kd, tid);
  stage_half<1>(Ag,      As0, Kd, tid);
  stage_half<3>(Bg,      Bs0, Kd, tid);
  stage_half<2>(Bg + 64, Bs1, Kd, tid);
  stage_half<0>(Ag + 64, As1, Kd, tid);
  stage_half<3>(Bg + 64, Bs1, Kd, tid);
  WAIT_VM(6);   // oldest 8 loads (K-tile 0) landed
  SBARRIER();

  frag af[4][2], b0[2][2], b1[2][2];

  for (int kt = 0; kt < NKT; ++kt) {
    const char* Ac = (kt & 1) ? As1 : As0;
    const char* Bc = (kt & 1) ? Bs1 : Bs0;
    char* An = (kt & 1) ? As0 : As1;
    bool s1 = (kt + 1) < NKT;
    bool s2 = (kt + 2) < NKT;
    const bf16* Ag1 = Ag + (size_t)(kt + 1) * 64;
    const bf16* Ag2 = Ag + (size_t)(kt + 2) * 64;
    const bf16* Bg2 = Bg + (size_t)(kt + 2) * 64;

    // ---- P0: (mh0, nh0); stage A1(t+1) -> other buf
#pragma unroll
    for (int mt = 0; mt < 4; ++mt) {
      af[mt][0] = lda(Ac, 0, mt, 0);
      af[mt][1] = lda(Ac, 0, mt, 1);
    }
#pragma unroll
    for (int nt = 0; nt < 2; ++nt) {
      b0[nt][0] = ldb(Bc, 0, nt, 0);
      b0[nt][1] = ldb(Bc, 0, nt, 1);
    }
    if (s1) stage_half<1>(Ag1, An, Kd, tid);
    SBARRIER(); WAIT_LGKM0();
    __builtin_amdgcn_s_setprio(1);
#pragma unroll
    for (int mt = 0; mt < 4; ++mt)
#pragma unroll
      for (int nt = 0; nt < 2; ++nt) {
        acc[mt][nt] = mfma16(af[mt][0], b0[nt][0], acc[mt][nt]);
        acc[mt][nt] = mfma16(af[mt][1], b0[nt][1], acc[mt][nt]);
      }
    __builtin_amdgcn_s_setprio(0);
    SBARRIER();

    // ---- P1: (mh0, nh1); stage B0(t+2) -> current buf (region dead since P0)
#pragma unroll
    for (int nt = 0; nt < 2; ++nt) {
      b1[nt][0] = ldb(Bc, 1, nt, 0);
      b1[nt][1] = ldb(Bc, 1, nt, 1);
    }
    if (s2) stage_half<2>(Bg2, (char*)Bc, Kd, tid);
    SBARRIER(); WAIT_LGKM0();
    __builtin_amdgcn_s_setprio(1);
#pragma unroll
    for (int mt = 0; mt < 4; ++mt)
#pragma unroll
      for (int nt = 0; nt < 2; ++nt) {
        acc[mt][2 + nt] = mfma16(af[mt][0], b1[nt][0], acc[mt][2 + nt]);
        acc[mt][2 + nt] = mfma16(af[mt][1], b1[nt][1], acc[mt][2 + nt]);
      }
    __builtin_amdgcn_s_setprio(0);
    SBARRIER();

    // ---- P2: (mh1, nh1); stage A0(t+2) (region dead since P0)
#pragma unroll
    for (int mt = 0; mt < 4; ++mt) {
      af[mt][0] = lda(Ac, 1, mt, 0);
      af[mt][1] = lda(Ac, 1, mt, 1);
    }
    if (s2) stage_half<0>(Ag2, (char*)Ac, Kd, tid);
    SBARRIER(); WAIT_LGKM0();
    __builtin_amdgcn_s_setprio(1);
#pragma unroll
    for (int mt = 0; mt < 4; ++mt)
#pragma unroll
      for (int nt = 0; nt < 2; ++nt) {
        acc[4 + mt][2 + nt] = mfma16(af[mt][0], b1[nt][0], acc[4 + mt][2 + nt]);
        acc[4 + mt][2 + nt] = mfma16(af[mt][1], b1[nt][1], acc[4 + mt][2 + nt]);
      }
    __builtin_amdgcn_s_setprio(0);
    SBARRIER();

    // ---- P3: (mh1, nh0); no ds_read (af from P2, b0 held since P0);
    //       stage B1(t+2) (region dead since P1); counted vmcnt at boundary
    if (s2) stage_half<3>(Bg2, (char*)Bc, Kd, tid);
    SBARRIER();
    __builtin_amdgcn_s_setprio(1);
#pragma unroll
    for (int mt = 0; mt < 4; ++mt)
#pragma unroll
      for (int nt = 0; nt < 2; ++nt) {
        acc[4 + mt][nt] = mfma16(af[mt][0], b0[nt][0], acc[4 + mt][nt]);
        acc[4 + mt][nt] = mfma16(af[mt][1], b0[nt][1], acc[4 + mt][nt]);
      }
    __builtin_amdgcn_s_setprio(0);
    if (s2)      { WAIT_VM(6); }   // {B0,A0,B1}(t+2) may stay in flight
    else if (s1) { WAIT_VM(0); }   // tail: drain so t+1 is fully ready
    SBARRIER();
  }

  // epilogue
#pragma unroll
  for (int mi = 0; mi < 8; ++mi)
#pragma unroll
    for (int ni = 0; ni < 4; ++ni)
#pragma unroll
      for (int r = 0; r < 4; ++r) {
        size_t row = bm + wm * 128 + mi * 16 + quad * 4 + r;
        size_t col = bn + wn * 64 + ni * 16 + ml;
        float v = acc[mi][ni][r];
        if (OUT_F32) ((float*)Cout)[row * Nn + col] = v;
        else         ((bf16*)Cout)[row * Nn + col] = f2b(v);
      }
}

// ---------------- RoPE (in place; q additionally prescaled by 1/sqrt(HD)) ----

__global__ void rope_kernel(bf16* __restrict__ qh, bf16* __restrict__ kvb,
                            const float* __restrict__ cosb, const float* __restrict__ sinb,
                            const int* __restrict__ positions) {
  const float qscale = 0.08838834764831843f;  // 1/sqrt(128), folded into q
  int idx   = blockIdx.x * blockDim.x + threadIdx.x;
  int token = idx / 2560;
  int p     = idx % 2560;
  int pos   = positions[token];
  bf16* base;
  int i;
  float sc;
  if (p < 2048) {  // q: 32 heads x 64 pairs
    int hh = p >> 6; i = p & 63;
    base = qh + (size_t)token * 4096 + hh * 128 + 2 * i;
    sc = qscale;
  } else {         // k: 8 heads x 64 pairs
    int pk = p - 2048;
    int hh = pk >> 6; i = pk & 63;
    base = kvb + (size_t)token * 2048 + hh * 128 + 2 * i;
    sc = 1.0f;
  }
  float c = cosb[pos * 64 + i] * sc, s = sinb[pos * 64 + i] * sc;
  float x1 = __bfloat162float(base[0]);
  float x2 = __bfloat162float(base[1]);
  base[0] = f2b(x1 * c - x2 * s);
  base[1] = f2b(x1 * s + x2 * c);
}

// ---------------- V transpose: kvb v-part [t][d] -> vt [b][kvh][d][t] -------

__global__ void vtrans_kernel(const bf16* __restrict__ kvb, bf16* __restrict__ vt) {
  __shared__ bf16 tile[32][33];
  int dt = blockIdx.x * 32;
  int tt = blockIdx.y * 32;
  int bk = blockIdx.z;
  int b = bk >> 3, kvh = bk & 7;
  const bf16* in = kvb + (size_t)(b * 1024) * 2048 + 1024 + kvh * 128;
  bf16* out = vt + (size_t)bk * 128 * 1024;
  int tx = threadIdx.x, ty = threadIdx.y;
#pragma unroll
  for (int i = 0; i < 32; i += 8)
    tile[ty + i][tx] = in[(size_t)(tt + ty + i) * 2048 + dt + tx];
  __syncthreads();
#pragma unroll
  for (int i = 0; i < 32; i += 8)
    out[(size_t)(dt + ty + i) * 1024 + tt + tx] = tile[tx][ty + i];
}

// ---------------- flash attention (GQA-shared K/V tiles) ----------------
// Block = 256 thr (4 waves) = (b, kvh, 16 q rows). Wave w handles head
// kvh*4+w on the SAME 16 q rows -> K/V LDS tiles shared 4x. K-tile = 64 rows.
// LDS K [64][128] and V [128][64] stored in 16B chunks with XOR swizzle
// (chunk-col ^= row&7): global_load_lds needs lane-linear LDS offsets, so the
// swizzle is applied by permuting the per-lane GLOBAL source address instead.

__global__ __launch_bounds__(256) void attn_kernel(
    const bf16* __restrict__ qh, const bf16* __restrict__ kvb,
    const bf16* __restrict__ vt, bf16* __restrict__ attn) {
  __shared__ alignas(16) bf16 Ks[64 * 128];   // 16KB
  __shared__ alignas(16) bf16 Vs[128 * 64];   // 16KB
  __shared__ alignas(16) bf16 Ps[4][16 * 80]; // 10KB, stride 80 (160B, 16B-mult)

  int tid  = threadIdx.x;
  int wave = tid >> 6;
  int lane = tid & 63;
  int ml   = lane & 15, quad = lane >> 4;

  int qt  = blockIdx.x;        // 0..63
  int kvh = blockIdx.y;        // 0..7
  int b   = blockIdx.z;        // 0..3
  int h   = kvh * 4 + wave;
  int q0  = qt * 16;

  const bf16* kbptr = kvb + (size_t)(b * 1024) * 2048 + kvh * 128;
  const bf16* vbptr = vt + (size_t)((b * 8 + kvh) * 128) * 1024;
  bf16* Pw = &Ps[wave][0];

  // Q fragments: rows q0+ml, head h, d = s*32 + quad*8 (already 1/sqrt(HD) scaled)
  frag qf[4];
  const bf16* qrow = qh + (size_t)(b * 1024 + q0 + ml) * 4096 + h * 128;
#pragma unroll
  for (int s = 0; s < 4; ++s) qf[s] = *(const frag*)(qrow + s * 32 + quad * 8);

  facc o[8];
#pragma unroll
  for (int db = 0; db < 8; ++db)
#pragma unroll
    for (int r = 0; r < 4; ++r) o[db][r] = 0.f;
  float m_i[4], l_i[4];
#pragma unroll
  for (int r = 0; r < 4; ++r) { m_i[r] = -1e30f; l_i[r] = 0.f; }

  int nkb = (qt >> 2) + 1;  // K tiles of 64 covering 0..q0+15

  for (int kb = 0; kb < nkb; ++kb) {
    int kbase = kb * 64;
    __syncthreads();  // prev iter's LDS reads done before restage
    // stage K tile: 1024 chunks of 16B; slot c holds global chunk (row, c&15 ^ row&7)
#pragma unroll
    for (int i = 0; i < 4; ++i) {
      int c = i * 256 + tid;
      int row = c >> 4, cs = c & 15;
      int gc = cs ^ (row & 7);
      async_copy16(kbptr + (size_t)(kbase + row) * 2048 + gc * 8, (char*)Ks + c * 16);
    }
    // stage V tile: [d][64 t], 8 chunks/row
#pragma unroll
    for (int i = 0; i < 4; ++i) {
      int c = i * 256 + tid;
      int d = c >> 3, cs = c & 7;
      int gc = cs ^ (d & 7);
      async_copy16(vbptr + (size_t)d * 1024 + kbase + gc * 8, (char*)Vs + c * 16);
    }
    __syncthreads();  // drains vmcnt -> tiles ready

    // QK^T: S[16q][64k] as 4 k-tiles of 16
    facc sc[4];
#pragma unroll
    for (int kt = 0; kt < 4; ++kt)
#pragma unroll
      for (int r = 0; r < 4; ++r) sc[kt][r] = 0.f;
#pragma unroll
    for (int s = 0; s < 4; ++s)
#pragma unroll
      for (int kt = 0; kt < 4; ++kt) {
        int row = kt * 16 + ml;
        int cs = ((s * 4 + quad) ^ (ml & 7));  // row&7 == ml&7
        frag kf = *(const frag*)&Ks[row * 128 + cs * 8];
        sc[kt] = __builtin_amdgcn_mfma_f32_16x16x32_bf16(qf[s], kf, sc[kt], 0, 0, 0);
      }

    // online softmax; mask predicate vacuously false off-diagonal
#pragma unroll
    for (int r = 0; r < 4; ++r) {
      int qp = q0 + quad * 4 + r;
      float v[4];
      float mx = -1e30f;
#pragma unroll
      for (int kt = 0; kt < 4; ++kt) {
        float s = sc[kt][r];
        if (qp < kbase + kt * 16 + ml) s = -1e30f;
        v[kt] = s;
        mx = fmaxf(mx, s);
      }
      mx = fmaxf(mx, __shfl_xor(mx, 1));
      mx = fmaxf(mx, __shfl_xor(mx, 2));
      mx = fmaxf(mx, __shfl_xor(mx, 4));
      mx = fmaxf(mx, __shfl_xor(mx, 8));
      float mnew  = fmaxf(m_i[r], mx);
      float alpha = __expf(m_i[r] - mnew);
      m_i[r] = mnew;
      float ps = 0.f;
#pragma unroll
      for (int kt = 0; kt < 4; ++kt) {
        float p = __expf(v[kt] - mnew);
        ps += p;
        Pw[(quad * 4 + r) * 80 + kt * 16 + ml] = f2b(p);
      }
      ps += __shfl_xor(ps, 1);
      ps += __shfl_xor(ps, 2);
      ps += __shfl_xor(ps, 4);
      ps += __shfl_xor(ps, 8);
      l_i[r] = l_i[r] * alpha + ps;
#pragma unroll
      for (int db = 0; db < 8; ++db) o[db][r] *= alpha;
    }
    __syncthreads();  // P visible (per-wave buffer; barrier for safe lgkm order)

    // PV: P[16q][64k] x V[64k][128d]
#pragma unroll
    for (int j = 0; j < 2; ++j) {
      frag pf = *(const frag*)&Pw[ml * 80 + j * 32 + quad * 8];
#pragma unroll
      for (int db = 0; db < 8; ++db) {
        int d = db * 16 + ml;
        int cs = ((j * 4 + quad) ^ (ml & 7));  // d&7 == ml&7
        frag vf = *(const frag*)&Vs[d * 64 + cs * 8];
        o[db] = __builtin_amdgcn_mfma_f32_16x16x32_bf16(pf, vf, o[db], 0, 0, 0);
      }
    }
  }

  bf16* arow = attn + (size_t)(b * 1024 + q0) * 4096 + h * 128;
#pragma unroll
  for (int db = 0; db < 8; ++db)
#pragma unroll
    for (int r = 0; r < 4; ++r) {
      float v = o[db][r] / l_i[r];
      arow[(size_t)(quad * 4 + r) * 4096 + db * 16 + ml] = f2b(v);
    }
}

// ---------------- launch ----------------

extern "C" void kernel_launch(void* const* d_in, const int* in_sizes, int n_in,
                              void* d_out, int out_size, void* d_ws, size_t ws_size,
                              hipStream_t stream) {
  const float* x        = (const float*)d_in[0];
  const float* w_q      = (const float*)d_in[1];
  const float* w_kv     = (const float*)d_in[2];
  const float* w_o      = (const float*)d_in[3];
  const float* rope_cos = (const float*)d_in[6];
  const float* rope_sin = (const float*)d_in[7];
  const int*   positions = (const int*)d_in[8];
  float* out = (float*)d_out;

  char* ws = (char*)d_ws;
  const size_t MB = 1024 * 1024;
  bf16* xb    = (bf16*)(ws + 0);
  bf16* wqT   = (bf16*)(ws + 32 * MB);
  bf16* wkvT  = (bf16*)(ws + 64 * MB);
  bf16* woT   = (bf16*)(ws + 80 * MB);
  bf16* qh    = (bf16*)(ws + 112 * MB);
  bf16* kvb   = (bf16*)(ws + 144 * MB);
  bf16* vt    = (bf16*)(ws + 160 * MB);
  bf16* attnb = xb;  // xb dead after kv GEMM

  static bool s_attr = false;
  if (!s_attr) {
    hipFuncSetAttribute(reinterpret_cast<const void*>(gemm256_kernel<false>),
                        hipFuncAttributeMaxDynamicSharedMemorySize, 131072);
    hipFuncSetAttribute(reinterpret_cast<const void*>(gemm256_kernel<true>),
                        hipFuncAttributeMaxDynamicSharedMemorySize, 131072);
    s_attr = true;
  }

  convert_x_kernel<<<16384, 256, 0, stream>>>(x, xb);
  transpose_conv_kernel<<<dim3(128, 128), dim3(32, 8), 0, stream>>>(w_q, wqT, 4096, 4096);
  transpose_conv_kernel<<<dim3(64, 128),  dim3(32, 8), 0, stream>>>(w_kv, wkvT, 4096, 2048);
  transpose_conv_kernel<<<dim3(128, 128), dim3(32, 8), 0, stream>>>(w_o, woT, 4096, 4096);

  gemm256_kernel<false><<<dim3(256), 512, 131072, stream>>>(xb, wqT, qh, 4096, 4096, 4096);
  gemm256_kernel<false><<<dim3(128), 512, 131072, stream>>>(xb, wkvT, kvb, 4096, 2048, 4096);

  rope_kernel<<<40960, 256, 0, stream>>>(qh, kvb, rope_cos, rope_sin, positions);
  vtrans_kernel<<<dim3(4, 32, 32), dim3(32, 8), 0, stream>>>(kvb, vt);

  attn_kernel<<<dim3(64, 8, 4), 256, 0, stream>>>(qh, kvb, vt, attnb);

  gemm256_kernel<true><<<dim3(256), 512, 131072, stream>>>(attnb, woT, out, 4096, 4096, 4096);
}

// Round 2
// 736.810 us; speedup vs baseline: 1.3169x; 1.0893x over previous
//
#include <hip/hip_runtime.h>
#include <hip/hip_bf16.h>

// ---------------------------------------------------------------------------
// StandardAttention: x -> q,k,v proj -> rope -> causal GQA attention -> o proj
// B=4 T=1024 DM=4096 H=32 KVH=8 HD=128 NREP=4. N = 4096 tokens.
//
// Round 2: attention restructured for balance + reuse:
//  - 512-thr blocks (8 waves = 2 q-subtiles x 4 heads) share each K/V LDS
//    tile 8x (was 4x).
//  - each block processes the balanced q-tile pair (31-p, p): every block
//    does exactly 17 K-tiles -> uniform work, grid 512 = exactly 2
//    resident blocks/CU (VGPR 4 waves/SIMD cap), no triangular tail.
//  - Ps stride 80 -> 84 bf16: quad-stride 672B == 8 banks mod 32 ->
//    conflict-free P write/read windows.
//
// Workspace layout (bytes):
//   xb    [4096][4096] bf16   off 0          32MB   (reused for attn out)
//   wqT   [4096][4096] bf16   off 32MB       32MB
//   wkvT  [2048][4096] bf16   off 64MB       16MB
//   woT   [4096][4096] bf16   off 80MB       32MB
//   qh    [4096][4096] bf16   off 112MB      32MB   (q proj, roped+prescaled)
//   kvb   [4096][2048] bf16   off 144MB      16MB   (k|v proj, k roped)
//   vt    [4][8][128][1024] bf16 off 160MB    8MB   (V^T for PV mfma B-frags)
// ---------------------------------------------------------------------------

typedef __hip_bfloat16 bf16;
using frag  = __attribute__((ext_vector_type(8))) short;  // 8 bf16 = 4 VGPR
using facc  = __attribute__((ext_vector_type(4))) float;  // 4 fp32 acc

static __device__ __forceinline__ bf16 f2b(float x) { return __float2bfloat16(x); }

static __device__ __forceinline__ void async_copy16(const void* g, void* l) {
  __builtin_amdgcn_global_load_lds(
      (const __attribute__((address_space(1))) void*)g,
      (__attribute__((address_space(3))) void*)l, 16, 0, 0);
}

static __device__ __forceinline__ facc mfma16(frag a, frag b, facc c) {
  return __builtin_amdgcn_mfma_f32_16x16x32_bf16(a, b, c, 0, 0, 0);
}

#define SBARRIER() do { __builtin_amdgcn_sched_barrier(0); \
                        __builtin_amdgcn_s_barrier(); \
                        __builtin_amdgcn_sched_barrier(0); } while (0)
#define WAIT_LGKM0() do { asm volatile("s_waitcnt lgkmcnt(0)" ::: "memory"); \
                          __builtin_amdgcn_sched_barrier(0); } while (0)
#define WAIT_VM(n) do { asm volatile("s_waitcnt vmcnt(" #n ")" ::: "memory"); \
                        __builtin_amdgcn_sched_barrier(0); } while (0)

// ---------------- conversion kernels ----------------

__global__ void convert_x_kernel(const float* __restrict__ in, bf16* __restrict__ out) {
  int i = (blockIdx.x * blockDim.x + threadIdx.x) * 4;
  float4 v = *(const float4*)(in + i);
  out[i + 0] = f2b(v.x);
  out[i + 1] = f2b(v.y);
  out[i + 2] = f2b(v.z);
  out[i + 3] = f2b(v.w);
}

// in[rows][cols] f32 -> out[cols][rows] bf16. grid (cols/32, rows/32), block (32,8)
__global__ void transpose_conv_kernel(const float* __restrict__ in, bf16* __restrict__ out,
                                      int rows, int cols) {
  __shared__ float tile[32][33];
  int bx = blockIdx.x * 32;
  int by = blockIdx.y * 32;
  int tx = threadIdx.x, ty = threadIdx.y;
#pragma unroll
  for (int i = 0; i < 32; i += 8)
    tile[ty + i][tx] = in[(size_t)(by + ty + i) * cols + bx + tx];
  __syncthreads();
#pragma unroll
  for (int i = 0; i < 32; i += 8)
    out[(size_t)(bx + ty + i) * rows + by + tx] = f2b(tile[tx][ty + i]);
}

// ---------------- 256x256 8-phase GEMM: C[M][N] = A[M][K] * BT[N][K]^T -----
// (unchanged from round 1; see comments there)

template <int KIND>  // 0=A0, 1=A1, 2=B0, 3=B1
static __device__ __forceinline__ void stage_half(const bf16* __restrict__ gsrc,
                                                  char* lds, int Kd, int tid) {
#pragma unroll
  for (int i = 0; i < 2; ++i) {
    int c = i * 512 + tid;
    int chunk;
    if (KIND < 2) chunk = c + ((c >> 9) << 9) + (KIND == 1 ? 512 : 0);
    else          chunk = c + ((c >> 8) << 8) + (KIND == 3 ? 256 : 0);
    int r  = chunk >> 3;
    int gc = (chunk & 7) ^ (r & 7);
    async_copy16(gsrc + (size_t)r * Kd + gc * 8, lds + (size_t)chunk * 16);
  }
}

template <bool OUT_F32>
__global__ __launch_bounds__(512, 2) void gemm256_kernel(
    const bf16* __restrict__ A, const bf16* __restrict__ BT,
    void* __restrict__ Cout, int M, int Nn, int Kd) {
  extern __shared__ char smem[];
  char* As0 = smem;
  char* As1 = smem + 32 * 1024;
  char* Bs0 = smem + 64 * 1024;
  char* Bs1 = smem + 96 * 1024;

  int tid  = threadIdx.x;
  int wave = tid >> 6, lane = tid & 63;
  int ml   = lane & 15, quad = lane >> 4;
  int wm   = wave >> 2, wn = wave & 3;

  int nbx = Nn >> 8;
  int nwg = gridDim.x;
  int id  = blockIdx.x;
  int swz = (id & 7) * (nwg >> 3) + (id >> 3);
  int bm  = (swz / nbx) << 8;
  int bn  = (swz % nbx) << 8;

  const bf16* Ag = A + (size_t)bm * Kd;
  const bf16* Bg = BT + (size_t)bn * Kd;

  facc acc[8][4];
#pragma unroll
  for (int i = 0; i < 8; ++i)
#pragma unroll
    for (int j = 0; j < 4; ++j)
#pragma unroll
      for (int r = 0; r < 4; ++r) acc[i][j][r] = 0.f;

  auto lda = [&](const char* buf, int mh, int mt, int kk) -> frag {
    int row = wm * 128 + mh * 64 + mt * 16 + ml;
    int cs  = (kk * 4 + quad) ^ (ml & 7);
    return *(const frag*)(buf + ((size_t)row * 8 + cs) * 16);
  };
  auto ldb = [&](const char* buf, int nh, int nt, int kk) -> frag {
    int row = wn * 64 + nh * 32 + nt * 16 + ml;
    int cs  = (kk * 4 + quad) ^ (ml & 7);
    return *(const frag*)(buf + ((size_t)row * 8 + cs) * 16);
  };

  int NKT = Kd >> 6;

  stage_half<0>(Ag,      As0, Kd, tid);
  stage_half<2>(Bg,      Bs0, Kd, tid);
  stage_half<1>(Ag,      As0, Kd, tid);
  stage_half<3>(Bg,      Bs0, Kd, tid);
  stage_half<2>(Bg + 64, Bs1, Kd, tid);
  stage_half<0>(Ag + 64, As1, Kd, tid);
  stage_half<3>(Bg + 64, Bs1, Kd, tid);
  WAIT_VM(6);
  SBARRIER();

  frag af[4][2], b0[2][2], b1[2][2];

  for (int kt = 0; kt < NKT; ++kt) {
    const char* Ac = (kt & 1) ? As1 : As0;
    const char* Bc = (kt & 1) ? Bs1 : Bs0;
    char* An = (kt & 1) ? As0 : As1;
    bool s1 = (kt + 1) < NKT;
    bool s2 = (kt + 2) < NKT;
    const bf16* Ag1 = Ag + (size_t)(kt + 1) * 64;
    const bf16* Ag2 = Ag + (size_t)(kt + 2) * 64;
    const bf16* Bg2 = Bg + (size_t)(kt + 2) * 64;

    // ---- P0: (mh0, nh0); stage A1(t+1)
#pragma unroll
    for (int mt = 0; mt < 4; ++mt) {
      af[mt][0] = lda(Ac, 0, mt, 0);
      af[mt][1] = lda(Ac, 0, mt, 1);
    }
#pragma unroll
    for (int nt = 0; nt < 2; ++nt) {
      b0[nt][0] = ldb(Bc, 0, nt, 0);
      b0[nt][1] = ldb(Bc, 0, nt, 1);
    }
    if (s1) stage_half<1>(Ag1, An, Kd, tid);
    SBARRIER(); WAIT_LGKM0();
    __builtin_amdgcn_s_setprio(1);
#pragma unroll
    for (int mt = 0; mt < 4; ++mt)
#pragma unroll
      for (int nt = 0; nt < 2; ++nt) {
        acc[mt][nt] = mfma16(af[mt][0], b0[nt][0], acc[mt][nt]);
        acc[mt][nt] = mfma16(af[mt][1], b0[nt][1], acc[mt][nt]);
      }
    __builtin_amdgcn_s_setprio(0);
    SBARRIER();

    // ---- P1: (mh0, nh1); stage B0(t+2)
#pragma unroll
    for (int nt = 0; nt < 2; ++nt) {
      b1[nt][0] = ldb(Bc, 1, nt, 0);
      b1[nt][1] = ldb(Bc, 1, nt, 1);
    }
    if (s2) stage_half<2>(Bg2, (char*)Bc, Kd, tid);
    SBARRIER(); WAIT_LGKM0();
    __builtin_amdgcn_s_setprio(1);
#pragma unroll
    for (int mt = 0; mt < 4; ++mt)
#pragma unroll
      for (int nt = 0; nt < 2; ++nt) {
        acc[mt][2 + nt] = mfma16(af[mt][0], b1[nt][0], acc[mt][2 + nt]);
        acc[mt][2 + nt] = mfma16(af[mt][1], b1[nt][1], acc[mt][2 + nt]);
      }
    __builtin_amdgcn_s_setprio(0);
    SBARRIER();

    // ---- P2: (mh1, nh1); stage A0(t+2)
#pragma unroll
    for (int mt = 0; mt < 4; ++mt) {
      af[mt][0] = lda(Ac, 1, mt, 0);
      af[mt][1] = lda(Ac, 1, mt, 1);
    }
    if (s2) stage_half<0>(Ag2, (char*)Ac, Kd, tid);
    SBARRIER(); WAIT_LGKM0();
    __builtin_amdgcn_s_setprio(1);
#pragma unroll
    for (int mt = 0; mt < 4; ++mt)
#pragma unroll
      for (int nt = 0; nt < 2; ++nt) {
        acc[4 + mt][2 + nt] = mfma16(af[mt][0], b1[nt][0], acc[4 + mt][2 + nt]);
        acc[4 + mt][2 + nt] = mfma16(af[mt][1], b1[nt][1], acc[4 + mt][2 + nt]);
      }
    __builtin_amdgcn_s_setprio(0);
    SBARRIER();

    // ---- P3: (mh1, nh0); stage B1(t+2); counted vmcnt at boundary
    if (s2) stage_half<3>(Bg2, (char*)Bc, Kd, tid);
    SBARRIER();
    __builtin_amdgcn_s_setprio(1);
#pragma unroll
    for (int mt = 0; mt < 4; ++mt)
#pragma unroll
      for (int nt = 0; nt < 2; ++nt) {
        acc[4 + mt][nt] = mfma16(af[mt][0], b0[nt][0], acc[4 + mt][nt]);
        acc[4 + mt][nt] = mfma16(af[mt][1], b0[nt][1], acc[4 + mt][nt]);
      }
    __builtin_amdgcn_s_setprio(0);
    if (s2)      { WAIT_VM(6); }
    else if (s1) { WAIT_VM(0); }
    SBARRIER();
  }

#pragma unroll
  for (int mi = 0; mi < 8; ++mi)
#pragma unroll
    for (int ni = 0; ni < 4; ++ni)
#pragma unroll
      for (int r = 0; r < 4; ++r) {
        size_t row = bm + wm * 128 + mi * 16 + quad * 4 + r;
        size_t col = bn + wn * 64 + ni * 16 + ml;
        float v = acc[mi][ni][r];
        if (OUT_F32) ((float*)Cout)[row * Nn + col] = v;
        else         ((bf16*)Cout)[row * Nn + col] = f2b(v);
      }
}

// ---------------- RoPE (in place; q additionally prescaled by 1/sqrt(HD)) ----

__global__ void rope_kernel(bf16* __restrict__ qh, bf16* __restrict__ kvb,
                            const float* __restrict__ cosb, const float* __restrict__ sinb,
                            const int* __restrict__ positions) {
  const float qscale = 0.08838834764831843f;  // 1/sqrt(128), folded into q
  int idx   = blockIdx.x * blockDim.x + threadIdx.x;
  int token = idx / 2560;
  int p     = idx % 2560;
  int pos   = positions[token];
  bf16* base;
  int i;
  float sc;
  if (p < 2048) {  // q: 32 heads x 64 pairs
    int hh = p >> 6; i = p & 63;
    base = qh + (size_t)token * 4096 + hh * 128 + 2 * i;
    sc = qscale;
  } else {         // k: 8 heads x 64 pairs
    int pk = p - 2048;
    int hh = pk >> 6; i = pk & 63;
    base = kvb + (size_t)token * 2048 + hh * 128 + 2 * i;
    sc = 1.0f;
  }
  float c = cosb[pos * 64 + i] * sc, s = sinb[pos * 64 + i] * sc;
  float x1 = __bfloat162float(base[0]);
  float x2 = __bfloat162float(base[1]);
  base[0] = f2b(x1 * c - x2 * s);
  base[1] = f2b(x1 * s + x2 * c);
}

// ---------------- V transpose: kvb v-part [t][d] -> vt [b][kvh][d][t] -------

__global__ void vtrans_kernel(const bf16* __restrict__ kvb, bf16* __restrict__ vt) {
  __shared__ bf16 tile[32][33];
  int dt = blockIdx.x * 32;
  int tt = blockIdx.y * 32;
  int bk = blockIdx.z;
  int b = bk >> 3, kvh = bk & 7;
  const bf16* in = kvb + (size_t)(b * 1024) * 2048 + 1024 + kvh * 128;
  bf16* out = vt + (size_t)bk * 128 * 1024;
  int tx = threadIdx.x, ty = threadIdx.y;
#pragma unroll
  for (int i = 0; i < 32; i += 8)
    tile[ty + i][tx] = in[(size_t)(tt + ty + i) * 2048 + dt + tx];
  __syncthreads();
#pragma unroll
  for (int i = 0; i < 32; i += 8)
    out[(size_t)(dt + ty + i) * 1024 + tt + tx] = tile[tx][ty + i];
}

// ---------------- flash attention (GQA + q-subtile shared K/V tiles) --------
// Block = 512 thr (8 waves) = (b, kvh, 32 q rows). Wave = (wq, wh):
// wq = q-subtile (16 rows), wh = head kvh*4+wh. All 8 waves share the K/V
// LDS tiles (8x reuse). Each block processes the q-tile PAIR (31-p, p):
// nkb(t) = t/2+1, so every block does exactly 17 K-tiles -> uniform load.
// Grid 16x8x4 = 512 blocks = exactly 2 resident blocks/CU.
// K-tile = 64 rows. LDS K [64][128], V [128][64] in 16B chunks with XOR
// swizzle (chunk-col ^= row&7) applied via pre-swizzled global source.
// Ps stride 84 bf16 (168B): quad row-stride 672B == 8 banks mod 32 ->
// P writes spread across all banks; read starts 10*ml mod 32 all distinct.

__global__ __launch_bounds__(512, 4) void attn_kernel(
    const bf16* __restrict__ qh, const bf16* __restrict__ kvb,
    const bf16* __restrict__ vt, bf16* __restrict__ attn) {
  __shared__ alignas(16) bf16 Ks[64 * 128];   // 16KB
  __shared__ alignas(16) bf16 Vs[128 * 64];   // 16KB
  __shared__ alignas(16) bf16 Ps[8][16 * 84]; // 21504B

  int tid  = threadIdx.x;
  int wave = tid >> 6;
  int lane = tid & 63;
  int ml   = lane & 15, quad = lane >> 4;
  int wq   = wave >> 2;        // q-subtile 0/1
  int wh   = wave & 3;         // head within kv group

  int pr  = blockIdx.x;        // 0..15 (pair index)
  int kvh = blockIdx.y;        // 0..7
  int b   = blockIdx.z;        // 0..3
  int h   = kvh * 4 + wh;

  const bf16* kbptr = kvb + (size_t)(b * 1024) * 2048 + kvh * 128;
  const bf16* vbptr = vt + (size_t)((b * 8 + kvh) * 128) * 1024;
  bf16* Pw = &Ps[wave][0];

#pragma unroll
  for (int half = 0; half < 2; ++half) {
    int qtile = half ? pr : (31 - pr);   // big tile first
    int q0 = qtile * 32 + wq * 16;

    // Q fragments: rows q0+ml, head h (already 1/sqrt(HD) scaled)
    frag qf[4];
    const bf16* qrow = qh + (size_t)(b * 1024 + q0 + ml) * 4096 + h * 128;
#pragma unroll
    for (int s = 0; s < 4; ++s) qf[s] = *(const frag*)(qrow + s * 32 + quad * 8);

    facc o[8];
#pragma unroll
    for (int db = 0; db < 8; ++db)
#pragma unroll
      for (int r = 0; r < 4; ++r) o[db][r] = 0.f;
    float m_i[4], l_i[4];
#pragma unroll
    for (int r = 0; r < 4; ++r) { m_i[r] = -1e30f; l_i[r] = 0.f; }

    int nkb = (qtile >> 1) + 1;  // K tiles of 64 covering 0..qtile*32+31

    for (int kb = 0; kb < nkb; ++kb) {
      int kbase = kb * 64;
      __syncthreads();  // prev LDS reads (and prev half's PV) done before restage
      // stage K tile: 1024 chunks of 16B over 512 threads
#pragma unroll
      for (int i = 0; i < 2; ++i) {
        int c = i * 512 + tid;
        int row = c >> 4, cs = c & 15;
        int gc = cs ^ (row & 7);
        async_copy16(kbptr + (size_t)(kbase + row) * 2048 + gc * 8, (char*)Ks + c * 16);
      }
      // stage V tile: [d][64 t], 8 chunks/row
#pragma unroll
      for (int i = 0; i < 2; ++i) {
        int c = i * 512 + tid;
        int d = c >> 3, cs = c & 7;
        int gc = cs ^ (d & 7);
        async_copy16(vbptr + (size_t)d * 1024 + kbase + gc * 8, (char*)Vs + c * 16);
      }
      __syncthreads();  // drains vmcnt -> tiles ready

      // QK^T: S[16q][64k] as 4 k-tiles of 16
      facc sc[4];
#pragma unroll
      for (int kt = 0; kt < 4; ++kt)
#pragma unroll
        for (int r = 0; r < 4; ++r) sc[kt][r] = 0.f;
#pragma unroll
      for (int s = 0; s < 4; ++s)
#pragma unroll
        for (int kt = 0; kt < 4; ++kt) {
          int row = kt * 16 + ml;
          int cs = ((s * 4 + quad) ^ (ml & 7));  // row&7 == ml&7
          frag kf = *(const frag*)&Ks[row * 128 + cs * 8];
          sc[kt] = __builtin_amdgcn_mfma_f32_16x16x32_bf16(qf[s], kf, sc[kt], 0, 0, 0);
        }

      // online softmax; causal mask
#pragma unroll
      for (int r = 0; r < 4; ++r) {
        int qp = q0 + quad * 4 + r;
        float v[4];
        float mx = -1e30f;
#pragma unroll
        for (int kt = 0; kt < 4; ++kt) {
          float s = sc[kt][r];
          if (qp < kbase + kt * 16 + ml) s = -1e30f;
          v[kt] = s;
          mx = fmaxf(mx, s);
        }
        mx = fmaxf(mx, __shfl_xor(mx, 1));
        mx = fmaxf(mx, __shfl_xor(mx, 2));
        mx = fmaxf(mx, __shfl_xor(mx, 4));
        mx = fmaxf(mx, __shfl_xor(mx, 8));
        float mnew  = fmaxf(m_i[r], mx);
        float alpha = __expf(m_i[r] - mnew);
        m_i[r] = mnew;
        float ps = 0.f;
#pragma unroll
        for (int kt = 0; kt < 4; ++kt) {
          float p = __expf(v[kt] - mnew);
          ps += p;
          Pw[(quad * 4 + r) * 84 + kt * 16 + ml] = f2b(p);
        }
        ps += __shfl_xor(ps, 1);
        ps += __shfl_xor(ps, 2);
        ps += __shfl_xor(ps, 4);
        ps += __shfl_xor(ps, 8);
        l_i[r] = l_i[r] * alpha + ps;
#pragma unroll
        for (int db = 0; db < 8; ++db) o[db][r] *= alpha;
      }
      __syncthreads();  // P visible (per-wave buffer; barrier for safe lgkm order)

      // PV: P[16q][64k] x V[64k][128d]
#pragma unroll
      for (int j = 0; j < 2; ++j) {
        frag pf = *(const frag*)&Pw[ml * 84 + j * 32 + quad * 8];
#pragma unroll
        for (int db = 0; db < 8; ++db) {
          int d = db * 16 + ml;
          int cs = ((j * 4 + quad) ^ (ml & 7));  // d&7 == ml&7
          frag vf = *(const frag*)&Vs[d * 64 + cs * 8];
          o[db] = __builtin_amdgcn_mfma_f32_16x16x32_bf16(pf, vf, o[db], 0, 0, 0);
        }
      }
    }

    bf16* arow = attn + (size_t)(b * 1024 + q0) * 4096 + h * 128;
#pragma unroll
    for (int db = 0; db < 8; ++db)
#pragma unroll
      for (int r = 0; r < 4; ++r) {
        float v = o[db][r] / l_i[r];
        arow[(size_t)(quad * 4 + r) * 4096 + db * 16 + ml] = f2b(v);
      }
  }
}

// ---------------- launch ----------------

extern "C" void kernel_launch(void* const* d_in, const int* in_sizes, int n_in,
                              void* d_out, int out_size, void* d_ws, size_t ws_size,
                              hipStream_t stream) {
  const float* x        = (const float*)d_in[0];
  const float* w_q      = (const float*)d_in[1];
  const float* w_kv     = (const float*)d_in[2];
  const float* w_o      = (const float*)d_in[3];
  const float* rope_cos = (const float*)d_in[6];
  const float* rope_sin = (const float*)d_in[7];
  const int*   positions = (const int*)d_in[8];
  float* out = (float*)d_out;

  char* ws = (char*)d_ws;
  const size_t MB = 1024 * 1024;
  bf16* xb    = (bf16*)(ws + 0);
  bf16* wqT   = (bf16*)(ws + 32 * MB);
  bf16* wkvT  = (bf16*)(ws + 64 * MB);
  bf16* woT   = (bf16*)(ws + 80 * MB);
  bf16* qh    = (bf16*)(ws + 112 * MB);
  bf16* kvb   = (bf16*)(ws + 144 * MB);
  bf16* vt    = (bf16*)(ws + 160 * MB);
  bf16* attnb = xb;  // xb dead after kv GEMM

  static bool s_attr = false;
  if (!s_attr) {
    hipFuncSetAttribute(reinterpret_cast<const void*>(gemm256_kernel<false>),
                        hipFuncAttributeMaxDynamicSharedMemorySize, 131072);
    hipFuncSetAttribute(reinterpret_cast<const void*>(gemm256_kernel<true>),
                        hipFuncAttributeMaxDynamicSharedMemorySize, 131072);
    s_attr = true;
  }

  convert_x_kernel<<<16384, 256, 0, stream>>>(x, xb);
  transpose_conv_kernel<<<dim3(128, 128), dim3(32, 8), 0, stream>>>(w_q, wqT, 4096, 4096);
  transpose_conv_kernel<<<dim3(64, 128),  dim3(32, 8), 0, stream>>>(w_kv, wkvT, 4096, 2048);
  transpose_conv_kernel<<<dim3(128, 128), dim3(32, 8), 0, stream>>>(w_o, woT, 4096, 4096);

  gemm256_kernel<false><<<dim3(256), 512, 131072, stream>>>(xb, wqT, qh, 4096, 4096, 4096);
  gemm256_kernel<false><<<dim3(128), 512, 131072, stream>>>(xb, wkvT, kvb, 4096, 2048, 4096);

  rope_kernel<<<40960, 256, 0, stream>>>(qh, kvb, rope_cos, rope_sin, positions);
  vtrans_kernel<<<dim3(4, 32, 32), dim3(32, 8), 0, stream>>>(kvb, vt);

  attn_kernel<<<dim3(16, 8, 4), 512, 0, stream>>>(qh, kvb, vt, attnb);

  gemm256_kernel<true><<<dim3(256), 512, 131072, stream>>>(attnb, woT, out, 4096, 4096, 4096);
}

// Round 3
// 708.452 us; speedup vs baseline: 1.3696x; 1.0400x over previous
//
#include <hip/hip_runtime.h>
#include <hip/hip_bf16.h>

// ---------------------------------------------------------------------------
// StandardAttention: x -> q,k,v proj -> rope -> causal GQA attention -> o proj
// B=4 T=1024 DM=4096 H=32 KVH=8 HD=128 NREP=4. N = 4096 tokens.
//
// Round 3: GEMM K-loop software-pipelined. Fragments for phase X are ds_read
// during phase X-1 (b0/b1 top-issued with a full MFMA window to drain; A
// frags mid-issued after their previous last use, reusing the same VGPRs).
// Phases start with counted lgkmcnt(4/0) instead of a full drain, so the
// LDS port and the MFMA pipe overlap. vmcnt(8) waits at ends of P0/P2/P3
// guard every pre-issued read (wait -> barrier -> read preserves the
// cross-wave landing guarantee). Loop unrolled x2 tiles for the b0
// register ping-pong (static indexing only).
//
// Workspace layout (bytes):
//   xb    [4096][4096] bf16   off 0          32MB   (reused for attn out)
//   wqT   [4096][4096] bf16   off 32MB       32MB
//   wkvT  [2048][4096] bf16   off 64MB       16MB
//   woT   [4096][4096] bf16   off 80MB       32MB
//   qh    [4096][4096] bf16   off 112MB      32MB   (q proj, roped+prescaled)
//   kvb   [4096][2048] bf16   off 144MB      16MB   (k|v proj, k roped)
//   vt    [4][8][128][1024] bf16 off 160MB    8MB   (V^T for PV mfma B-frags)
// ---------------------------------------------------------------------------

typedef __hip_bfloat16 bf16;
using frag  = __attribute__((ext_vector_type(8))) short;  // 8 bf16 = 4 VGPR
using facc  = __attribute__((ext_vector_type(4))) float;  // 4 fp32 acc

static __device__ __forceinline__ bf16 f2b(float x) { return __float2bfloat16(x); }

static __device__ __forceinline__ void async_copy16(const void* g, void* l) {
  __builtin_amdgcn_global_load_lds(
      (const __attribute__((address_space(1))) void*)g,
      (__attribute__((address_space(3))) void*)l, 16, 0, 0);
}

static __device__ __forceinline__ facc mfma16(frag a, frag b, facc c) {
  return __builtin_amdgcn_mfma_f32_16x16x32_bf16(a, b, c, 0, 0, 0);
}

#define SBARRIER() do { __builtin_amdgcn_sched_barrier(0); \
                        __builtin_amdgcn_s_barrier(); \
                        __builtin_amdgcn_sched_barrier(0); } while (0)
#define WAIT_LGKM(n) do { asm volatile("s_waitcnt lgkmcnt(" #n ")" ::: "memory"); \
                          __builtin_amdgcn_sched_barrier(0); } while (0)
#define WAIT_VM(n) do { asm volatile("s_waitcnt vmcnt(" #n ")" ::: "memory"); \
                        __builtin_amdgcn_sched_barrier(0); } while (0)
#define SCHEDBAR() __builtin_amdgcn_sched_barrier(0)
#define PRIO1 __builtin_amdgcn_s_setprio(1)
#define PRIO0 __builtin_amdgcn_s_setprio(0)

// ---------------- conversion kernels ----------------

__global__ void convert_x_kernel(const float* __restrict__ in, bf16* __restrict__ out) {
  int i = (blockIdx.x * blockDim.x + threadIdx.x) * 4;
  float4 v = *(const float4*)(in + i);
  out[i + 0] = f2b(v.x);
  out[i + 1] = f2b(v.y);
  out[i + 2] = f2b(v.z);
  out[i + 3] = f2b(v.w);
}

// in[rows][cols] f32 -> out[cols][rows] bf16. grid (cols/32, rows/32), block (32,8)
__global__ void transpose_conv_kernel(const float* __restrict__ in, bf16* __restrict__ out,
                                      int rows, int cols) {
  __shared__ float tile[32][33];
  int bx = blockIdx.x * 32;
  int by = blockIdx.y * 32;
  int tx = threadIdx.x, ty = threadIdx.y;
#pragma unroll
  for (int i = 0; i < 32; i += 8)
    tile[ty + i][tx] = in[(size_t)(by + ty + i) * cols + bx + tx];
  __syncthreads();
#pragma unroll
  for (int i = 0; i < 32; i += 8)
    out[(size_t)(bx + ty + i) * rows + by + tx] = f2b(tile[tx][ty + i]);
}

// ---------------- 256x256 8-phase GEMM: C[M][N] = A[M][K] * BT[N][K]^T -----
// Tiles: BM=BN=256, BK=64. 512 thr = 8 waves (2M x 4N). Per-wave out 128x64.
// LDS 128KB: A dbuf 2x32KB + B dbuf 2x32KB, 16B chunks, XOR swizzle via
// pre-swizzled global source (conflict-free, verified: SQ_LDS_BANK_CONFLICT=0).
//
// Read pipeline (per tile t, quadrants P0=(mh0,n0) P1=(mh0,n1) P2=(mh1,n1)
// P3=(mh1,n0)):
//   b0(t):  top-P3(t-1)  [4 rd, ping-pong regs]   -> used P0(t), P3(t)
//   af0(t): mid-P3(t-1)  [8 rd, reuses af regs]   -> used P0(t), P1(t)
//   b1(t):  top-P0(t)    [4 rd]                   -> used P1(t), P2(t)
//   af1(t): mid-P1(t)    [8 rd, reuses af regs]   -> used P2(t), P3(t)
// lgkm: P0 cnt(4), P1 cnt(0), P2 cnt(0), P3 none.
// Stage slots (unchanged): P0: A1(t+1)->An; P1: B0(t+2)->Bc; P2: A0(t+2)->Ac;
// P3: B1(t+2)->Bc.  vmcnt(8) at end of P0/P2/P3 guards the pre-issued reads
// (each wait precedes the dependent read's barrier; counts derived from the
// fixed issue order ...B1(t),A1(t),B0(t+1),A0(t+1),B1(t+1),[A1(t+2)...]).

template <int KIND>  // 0=A0, 1=A1, 2=B0, 3=B1
static __device__ __forceinline__ void stage_half(const bf16* __restrict__ gsrc,
                                                  char* lds, int Kd, int tid) {
#pragma unroll
  for (int i = 0; i < 2; ++i) {
    int c = i * 512 + tid;
    int chunk;
    if (KIND < 2) chunk = c + ((c >> 9) << 9) + (KIND == 1 ? 512 : 0);
    else          chunk = c + ((c >> 8) << 8) + (KIND == 3 ? 256 : 0);
    int r  = chunk >> 3;
    int gc = (chunk & 7) ^ (r & 7);
    async_copy16(gsrc + (size_t)r * Kd + gc * 8, lds + (size_t)chunk * 16);
  }
}

#define RDA(DST, BUF, MH)                                         \
  _Pragma("unroll")                                               \
  for (int mt = 0; mt < 4; ++mt) {                                \
    DST[mt][0] = lda(BUF, MH, mt, 0);                             \
    DST[mt][1] = lda(BUF, MH, mt, 1);                             \
  }

#define RDB(DST, BUF, NH)                                         \
  _Pragma("unroll")                                               \
  for (int nt = 0; nt < 2; ++nt) {                                \
    DST[nt][0] = ldb(BUF, NH, nt, 0);                             \
    DST[nt][1] = ldb(BUF, NH, nt, 1);                             \
  }

#define MFMA_Q(AF, BF, MB, NB)                                    \
  _Pragma("unroll")                                               \
  for (int mt = 0; mt < 4; ++mt)                                  \
    _Pragma("unroll")                                             \
    for (int nt = 0; nt < 2; ++nt) {                              \
      acc[(MB) + mt][(NB) + nt] =                                 \
          mfma16(AF[mt][0], BF[nt][0], acc[(MB) + mt][(NB) + nt]);\
      acc[(MB) + mt][(NB) + nt] =                                 \
          mfma16(AF[mt][1], BF[nt][1], acc[(MB) + mt][(NB) + nt]);\
    }

// One K-tile (4 phases). AC/BC: current bufs; AN/BN: other bufs.
// B0C: this tile's b0 regs; B0N: next tile's b0 regs.
#define GTILE(AC, BC, AN, BN, B0C, B0N, T)                        \
  {                                                               \
    bool s1 = (T) + 1 < NKT;                                      \
    bool s2 = (T) + 2 < NKT;                                      \
    const bf16* Ag1 = Ag + (size_t)((T) + 1) * 64;                \
    const bf16* Ag2 = Ag + (size_t)((T) + 2) * 64;                \
    const bf16* Bg2 = Bg + (size_t)((T) + 2) * 64;                \
    /* ---- P0: MFMA af0 x b0 ---- */                             \
    if (s1) stage_half<1>(Ag1, AN, Kd, tid);                      \
    RDB(b1, BC, 1);                                               \
    SBARRIER();                                                   \
    WAIT_LGKM(4);                                                 \
    PRIO1; MFMA_Q(af, B0C, 0, 0); PRIO0;                          \
    WAIT_VM(8);                                                   \
    SBARRIER();                                                   \
    /* ---- P1: MFMA af0 x b1; mid-issue af1 ---- */              \
    if (s2) stage_half<2>(Bg2, (char*)(BC), Kd, tid);             \
    SBARRIER();                                                   \
    WAIT_LGKM(0);                                                 \
    PRIO1; MFMA_Q(af, b1, 0, 2); PRIO0;                           \
    SCHEDBAR();                                                   \
    RDA(af, AC, 1);                                               \
    SBARRIER();                                                   \
    /* ---- P2: MFMA af1 x b1 ---- */                             \
    if (s2) stage_half<0>(Ag2, (char*)(AC), Kd, tid);             \
    SBARRIER();                                                   \
    WAIT_LGKM(0);                                                 \
    PRIO1; MFMA_Q(af, b1, 4, 2); PRIO0;                           \
    WAIT_VM(8);                                                   \
    SBARRIER();                                                   \
    /* ---- P3: MFMA af1 x b0; top: b0(t+1); mid: af0(t+1) ---- */\
    if (s2) stage_half<3>(Bg2, (char*)(BC), Kd, tid);             \
    if (s1) { RDB(B0N, BN, 0); }                                  \
    SBARRIER();                                                   \
    PRIO1; MFMA_Q(af, B0C, 4, 0); PRIO0;                          \
    SCHEDBAR();                                                   \
    if (s1) { RDA(af, AN, 0); }                                   \
    WAIT_VM(8);                                                   \
    SBARRIER();                                                   \
  }

template <bool OUT_F32>
__global__ __launch_bounds__(512, 2) void gemm256_kernel(
    const bf16* __restrict__ A, const bf16* __restrict__ BT,
    void* __restrict__ Cout, int M, int Nn, int Kd) {
  extern __shared__ char smem[];
  char* As0 = smem;
  char* As1 = smem + 32 * 1024;
  char* Bs0 = smem + 64 * 1024;
  char* Bs1 = smem + 96 * 1024;

  int tid  = threadIdx.x;
  int wave = tid >> 6, lane = tid & 63;
  int ml   = lane & 15, quad = lane >> 4;
  int wm   = wave >> 2, wn = wave & 3;

  // XCD-aware bijective swizzle (grid % 8 == 0 for all our shapes)
  int nbx = Nn >> 8;
  int nwg = gridDim.x;
  int id  = blockIdx.x;
  int swz = (id & 7) * (nwg >> 3) + (id >> 3);
  int bm  = (swz / nbx) << 8;
  int bn  = (swz % nbx) << 8;

  const bf16* Ag = A + (size_t)bm * Kd;
  const bf16* Bg = BT + (size_t)bn * Kd;

  facc acc[8][4];
#pragma unroll
  for (int i = 0; i < 8; ++i)
#pragma unroll
    for (int j = 0; j < 4; ++j)
#pragma unroll
      for (int r = 0; r < 4; ++r) acc[i][j][r] = 0.f;

  auto lda = [&](const char* buf, int mh, int mt, int kk) -> frag {
    int row = wm * 128 + mh * 64 + mt * 16 + ml;        // row&7 == ml&7
    int cs  = (kk * 4 + quad) ^ (ml & 7);
    return *(const frag*)(buf + ((size_t)row * 8 + cs) * 16);
  };
  auto ldb = [&](const char* buf, int nh, int nt, int kk) -> frag {
    int row = wn * 64 + nh * 32 + nt * 16 + ml;         // row&7 == ml&7
    int cs  = (kk * 4 + quad) ^ (ml & 7);
    return *(const frag*)(buf + ((size_t)row * 8 + cs) * 16);
  };

  int NKT = Kd >> 6;

  frag af[4][2], b0e[2][2], b0o[2][2], b1[2][2];

  // prologue: K-tile 0 complete + 3 half-tiles of K-tile 1, issue order
  // matching the steady-state vm accounting; then pre-read b0(0)/af0(0).
  stage_half<2>(Bg,      Bs0, Kd, tid);   // B0(0)
  stage_half<0>(Ag,      As0, Kd, tid);   // A0(0)
  stage_half<3>(Bg,      Bs0, Kd, tid);   // B1(0)
  stage_half<1>(Ag,      As0, Kd, tid);   // A1(0)
  stage_half<2>(Bg + 64, Bs1, Kd, tid);   // B0(1)
  stage_half<0>(Ag + 64, As1, Kd, tid);   // A0(1)
  stage_half<3>(Bg + 64, Bs1, Kd, tid);   // B1(1)
  WAIT_VM(10);   // B0(0), A0(0) landed (all waves wait, then barrier)
  SBARRIER();
  RDB(b0e, Bs0, 0);    // b0(0)
  SCHEDBAR();
  RDA(af, As0, 0);     // af0(0)
  WAIT_VM(8);    // B1(0) landed (guards b1(0) read at P0(0) top)
  SBARRIER();

  for (int kt = 0; kt < NKT; kt += 2) {
    GTILE(As0, Bs0, As1, Bs1, b0e, b0o, kt);
    GTILE(As1, Bs1, As0, Bs0, b0o, b0e, kt + 1);
  }

  // epilogue
#pragma unroll
  for (int mi = 0; mi < 8; ++mi)
#pragma unroll
    for (int ni = 0; ni < 4; ++ni)
#pragma unroll
      for (int r = 0; r < 4; ++r) {
        size_t row = bm + wm * 128 + mi * 16 + quad * 4 + r;
        size_t col = bn + wn * 64 + ni * 16 + ml;
        float v = acc[mi][ni][r];
        if (OUT_F32) ((float*)Cout)[row * Nn + col] = v;
        else         ((bf16*)Cout)[row * Nn + col] = f2b(v);
      }
}

// ---------------- RoPE (in place; q additionally prescaled by 1/sqrt(HD)) ----

__global__ void rope_kernel(bf16* __restrict__ qh, bf16* __restrict__ kvb,
                            const float* __restrict__ cosb, const float* __restrict__ sinb,
                            const int* __restrict__ positions) {
  const float qscale = 0.08838834764831843f;  // 1/sqrt(128), folded into q
  int idx   = blockIdx.x * blockDim.x + threadIdx.x;
  int token = idx / 2560;
  int p     = idx % 2560;
  int pos   = positions[token];
  bf16* base;
  int i;
  float sc;
  if (p < 2048) {  // q: 32 heads x 64 pairs
    int hh = p >> 6; i = p & 63;
    base = qh + (size_t)token * 4096 + hh * 128 + 2 * i;
    sc = qscale;
  } else {         // k: 8 heads x 64 pairs
    int pk = p - 2048;
    int hh = pk >> 6; i = pk & 63;
    base = kvb + (size_t)token * 2048 + hh * 128 + 2 * i;
    sc = 1.0f;
  }
  float c = cosb[pos * 64 + i] * sc, s = sinb[pos * 64 + i] * sc;
  float x1 = __bfloat162float(base[0]);
  float x2 = __bfloat162float(base[1]);
  base[0] = f2b(x1 * c - x2 * s);
  base[1] = f2b(x1 * s + x2 * c);
}

// ---------------- V transpose: kvb v-part [t][d] -> vt [b][kvh][d][t] -------

__global__ void vtrans_kernel(const bf16* __restrict__ kvb, bf16* __restrict__ vt) {
  __shared__ bf16 tile[32][33];
  int dt = blockIdx.x * 32;
  int tt = blockIdx.y * 32;
  int bk = blockIdx.z;
  int b = bk >> 3, kvh = bk & 7;
  const bf16* in = kvb + (size_t)(b * 1024) * 2048 + 1024 + kvh * 128;
  bf16* out = vt + (size_t)bk * 128 * 1024;
  int tx = threadIdx.x, ty = threadIdx.y;
#pragma unroll
  for (int i = 0; i < 32; i += 8)
    tile[ty + i][tx] = in[(size_t)(tt + ty + i) * 2048 + dt + tx];
  __syncthreads();
#pragma unroll
  for (int i = 0; i < 32; i += 8)
    out[(size_t)(dt + ty + i) * 1024 + tt + tx] = tile[tx][ty + i];
}

// ---------------- flash attention (GQA + q-subtile shared K/V tiles) --------
// (unchanged from round 2; see comments there)

__global__ __launch_bounds__(512, 4) void attn_kernel(
    const bf16* __restrict__ qh, const bf16* __restrict__ kvb,
    const bf16* __restrict__ vt, bf16* __restrict__ attn) {
  __shared__ alignas(16) bf16 Ks[64 * 128];   // 16KB
  __shared__ alignas(16) bf16 Vs[128 * 64];   // 16KB
  __shared__ alignas(16) bf16 Ps[8][16 * 84]; // 21504B

  int tid  = threadIdx.x;
  int wave = tid >> 6;
  int lane = tid & 63;
  int ml   = lane & 15, quad = lane >> 4;
  int wq   = wave >> 2;        // q-subtile 0/1
  int wh   = wave & 3;         // head within kv group

  int pr  = blockIdx.x;        // 0..15 (pair index)
  int kvh = blockIdx.y;        // 0..7
  int b   = blockIdx.z;        // 0..3
  int h   = kvh * 4 + wh;

  const bf16* kbptr = kvb + (size_t)(b * 1024) * 2048 + kvh * 128;
  const bf16* vbptr = vt + (size_t)((b * 8 + kvh) * 128) * 1024;
  bf16* Pw = &Ps[wave][0];

#pragma unroll
  for (int half = 0; half < 2; ++half) {
    int qtile = half ? pr : (31 - pr);   // big tile first
    int q0 = qtile * 32 + wq * 16;

    // Q fragments: rows q0+ml, head h (already 1/sqrt(HD) scaled)
    frag qf[4];
    const bf16* qrow = qh + (size_t)(b * 1024 + q0 + ml) * 4096 + h * 128;
#pragma unroll
    for (int s = 0; s < 4; ++s) qf[s] = *(const frag*)(qrow + s * 32 + quad * 8);

    facc o[8];
#pragma unroll
    for (int db = 0; db < 8; ++db)
#pragma unroll
      for (int r = 0; r < 4; ++r) o[db][r] = 0.f;
    float m_i[4], l_i[4];
#pragma unroll
    for (int r = 0; r < 4; ++r) { m_i[r] = -1e30f; l_i[r] = 0.f; }

    int nkb = (qtile >> 1) + 1;  // K tiles of 64 covering 0..qtile*32+31

    for (int kb = 0; kb < nkb; ++kb) {
      int kbase = kb * 64;
      __syncthreads();  // prev LDS reads (and prev half's PV) done before restage
      // stage K tile: 1024 chunks of 16B over 512 threads
#pragma unroll
      for (int i = 0; i < 2; ++i) {
        int c = i * 512 + tid;
        int row = c >> 4, cs = c & 15;
        int gc = cs ^ (row & 7);
        async_copy16(kbptr + (size_t)(kbase + row) * 2048 + gc * 8, (char*)Ks + c * 16);
      }
      // stage V tile: [d][64 t], 8 chunks/row
#pragma unroll
      for (int i = 0; i < 2; ++i) {
        int c = i * 512 + tid;
        int d = c >> 3, cs = c & 7;
        int gc = cs ^ (d & 7);
        async_copy16(vbptr + (size_t)d * 1024 + kbase + gc * 8, (char*)Vs + c * 16);
      }
      __syncthreads();  // drains vmcnt -> tiles ready

      // QK^T: S[16q][64k] as 4 k-tiles of 16
      facc sc[4];
#pragma unroll
      for (int kt = 0; kt < 4; ++kt)
#pragma unroll
        for (int r = 0; r < 4; ++r) sc[kt][r] = 0.f;
#pragma unroll
      for (int s = 0; s < 4; ++s)
#pragma unroll
        for (int kt = 0; kt < 4; ++kt) {
          int row = kt * 16 + ml;
          int cs = ((s * 4 + quad) ^ (ml & 7));  // row&7 == ml&7
          frag kf = *(const frag*)&Ks[row * 128 + cs * 8];
          sc[kt] = __builtin_amdgcn_mfma_f32_16x16x32_bf16(qf[s], kf, sc[kt], 0, 0, 0);
        }

      // online softmax; causal mask
#pragma unroll
      for (int r = 0; r < 4; ++r) {
        int qp = q0 + quad * 4 + r;
        float v[4];
        float mx = -1e30f;
#pragma unroll
        for (int kt = 0; kt < 4; ++kt) {
          float s = sc[kt][r];
          if (qp < kbase + kt * 16 + ml) s = -1e30f;
          v[kt] = s;
          mx = fmaxf(mx, s);
        }
        mx = fmaxf(mx, __shfl_xor(mx, 1));
        mx = fmaxf(mx, __shfl_xor(mx, 2));
        mx = fmaxf(mx, __shfl_xor(mx, 4));
        mx = fmaxf(mx, __shfl_xor(mx, 8));
        float mnew  = fmaxf(m_i[r], mx);
        float alpha = __expf(m_i[r] - mnew);
        m_i[r] = mnew;
        float ps = 0.f;
#pragma unroll
        for (int kt = 0; kt < 4; ++kt) {
          float p = __expf(v[kt] - mnew);
          ps += p;
          Pw[(quad * 4 + r) * 84 + kt * 16 + ml] = f2b(p);
        }
        ps += __shfl_xor(ps, 1);
        ps += __shfl_xor(ps, 2);
        ps += __shfl_xor(ps, 4);
        ps += __shfl_xor(ps, 8);
        l_i[r] = l_i[r] * alpha + ps;
#pragma unroll
        for (int db = 0; db < 8; ++db) o[db][r] *= alpha;
      }
      __syncthreads();  // P visible (per-wave buffer; barrier for safe lgkm order)

      // PV: P[16q][64k] x V[64k][128d]
#pragma unroll
      for (int j = 0; j < 2; ++j) {
        frag pf = *(const frag*)&Pw[ml * 84 + j * 32 + quad * 8];
#pragma unroll
        for (int db = 0; db < 8; ++db) {
          int d = db * 16 + ml;
          int cs = ((j * 4 + quad) ^ (ml & 7));  // d&7 == ml&7
          frag vf = *(const frag*)&Vs[d * 64 + cs * 8];
          o[db] = __builtin_amdgcn_mfma_f32_16x16x32_bf16(pf, vf, o[db], 0, 0, 0);
        }
      }
    }

    bf16* arow = attn + (size_t)(b * 1024 + q0) * 4096 + h * 128;
#pragma unroll
    for (int db = 0; db < 8; ++db)
#pragma unroll
      for (int r = 0; r < 4; ++r) {
        float v = o[db][r] / l_i[r];
        arow[(size_t)(quad * 4 + r) * 4096 + db * 16 + ml] = f2b(v);
      }
  }
}

// ---------------- launch ----------------

extern "C" void kernel_launch(void* const* d_in, const int* in_sizes, int n_in,
                              void* d_out, int out_size, void* d_ws, size_t ws_size,
                              hipStream_t stream) {
  const float* x        = (const float*)d_in[0];
  const float* w_q      = (const float*)d_in[1];
  const float* w_kv     = (const float*)d_in[2];
  const float* w_o      = (const float*)d_in[3];
  const float* rope_cos = (const float*)d_in[6];
  const float* rope_sin = (const float*)d_in[7];
  const int*   positions = (const int*)d_in[8];
  float* out = (float*)d_out;

  char* ws = (char*)d_ws;
  const size_t MB = 1024 * 1024;
  bf16* xb    = (bf16*)(ws + 0);
  bf16* wqT   = (bf16*)(ws + 32 * MB);
  bf16* wkvT  = (bf16*)(ws + 64 * MB);
  bf16* woT   = (bf16*)(ws + 80 * MB);
  bf16* qh    = (bf16*)(ws + 112 * MB);
  bf16* kvb   = (bf16*)(ws + 144 * MB);
  bf16* vt    = (bf16*)(ws + 160 * MB);
  bf16* attnb = xb;  // xb dead after kv GEMM

  static bool s_attr = false;
  if (!s_attr) {
    hipFuncSetAttribute(reinterpret_cast<const void*>(gemm256_kernel<false>),
                        hipFuncAttributeMaxDynamicSharedMemorySize, 131072);
    hipFuncSetAttribute(reinterpret_cast<const void*>(gemm256_kernel<true>),
                        hipFuncAttributeMaxDynamicSharedMemorySize, 131072);
    s_attr = true;
  }

  convert_x_kernel<<<16384, 256, 0, stream>>>(x, xb);
  transpose_conv_kernel<<<dim3(128, 128), dim3(32, 8), 0, stream>>>(w_q, wqT, 4096, 4096);
  transpose_conv_kernel<<<dim3(64, 128),  dim3(32, 8), 0, stream>>>(w_kv, wkvT, 4096, 2048);
  transpose_conv_kernel<<<dim3(128, 128), dim3(32, 8), 0, stream>>>(w_o, woT, 4096, 4096);

  gemm256_kernel<false><<<dim3(256), 512, 131072, stream>>>(xb, wqT, qh, 4096, 4096, 4096);
  gemm256_kernel<false><<<dim3(128), 512, 131072, stream>>>(xb, wkvT, kvb, 4096, 2048, 4096);

  rope_kernel<<<40960, 256, 0, stream>>>(qh, kvb, rope_cos, rope_sin, positions);
  vtrans_kernel<<<dim3(4, 32, 32), dim3(32, 8), 0, stream>>>(kvb, vt);

  attn_kernel<<<dim3(16, 8, 4), 512, 0, stream>>>(qh, kvb, vt, attnb);

  gemm256_kernel<true><<<dim3(256), 512, 131072, stream>>>(attnb, woT, out, 4096, 4096, 4096);
}

// Round 4
// 685.822 us; speedup vs baseline: 1.4148x; 1.0330x over previous
//
#include <hip/hip_runtime.h>
#include <hip/hip_bf16.h>

// ---------------------------------------------------------------------------
// StandardAttention: x -> q,k,v proj -> rope -> causal GQA attention -> o proj
// B=4 T=1024 DM=4096 H=32 KVH=8 HD=128 NREP=4. N = 4096 tokens.
//
// Round 4: kv projection gets its own GEMM shape. The 256x256-tile kernel
// gave kv only 128 blocks -> half the CUs idle for a full ~128us dispatch.
// New gemm_kv_kernel: BM=256 x BN=128 -> 16x16 = 256 blocks (full GPU),
// 8 waves = 4M x 2N, per-wave 64x64 (acc 64 regs), 2 phases/K-tile of
// 16-MFMA clusters, same XOR chunk swizzle (0 conflicts), counted vmcnt
// (6/6 steady state) re-derived for the 4-stage/tile pipeline. LDS 96KB.
// q-proj / o-proj keep the round-3 software-pipelined 256x256 kernel.
//
// Workspace layout (bytes):
//   xb    [4096][4096] bf16   off 0          32MB   (reused for attn out)
//   wqT   [4096][4096] bf16   off 32MB       32MB
//   wkvT  [2048][4096] bf16   off 64MB       16MB
//   woT   [4096][4096] bf16   off 80MB       32MB
//   qh    [4096][4096] bf16   off 112MB      32MB   (q proj, roped+prescaled)
//   kvb   [4096][2048] bf16   off 144MB      16MB   (k|v proj, k roped)
//   vt    [4][8][128][1024] bf16 off 160MB    8MB   (V^T for PV mfma B-frags)
// ---------------------------------------------------------------------------

typedef __hip_bfloat16 bf16;
using frag  = __attribute__((ext_vector_type(8))) short;  // 8 bf16 = 4 VGPR
using facc  = __attribute__((ext_vector_type(4))) float;  // 4 fp32 acc

static __device__ __forceinline__ bf16 f2b(float x) { return __float2bfloat16(x); }

static __device__ __forceinline__ void async_copy16(const void* g, void* l) {
  __builtin_amdgcn_global_load_lds(
      (const __attribute__((address_space(1))) void*)g,
      (__attribute__((address_space(3))) void*)l, 16, 0, 0);
}

static __device__ __forceinline__ facc mfma16(frag a, frag b, facc c) {
  return __builtin_amdgcn_mfma_f32_16x16x32_bf16(a, b, c, 0, 0, 0);
}

#define SBARRIER() do { __builtin_amdgcn_sched_barrier(0); \
                        __builtin_amdgcn_s_barrier(); \
                        __builtin_amdgcn_sched_barrier(0); } while (0)
#define WAIT_LGKM(n) do { asm volatile("s_waitcnt lgkmcnt(" #n ")" ::: "memory"); \
                          __builtin_amdgcn_sched_barrier(0); } while (0)
#define WAIT_VM(n) do { asm volatile("s_waitcnt vmcnt(" #n ")" ::: "memory"); \
                        __builtin_amdgcn_sched_barrier(0); } while (0)
#define SCHEDBAR() __builtin_amdgcn_sched_barrier(0)
#define PRIO1 __builtin_amdgcn_s_setprio(1)
#define PRIO0 __builtin_amdgcn_s_setprio(0)

// ---------------- conversion kernels ----------------

__global__ void convert_x_kernel(const float* __restrict__ in, bf16* __restrict__ out) {
  int i = (blockIdx.x * blockDim.x + threadIdx.x) * 4;
  float4 v = *(const float4*)(in + i);
  out[i + 0] = f2b(v.x);
  out[i + 1] = f2b(v.y);
  out[i + 2] = f2b(v.z);
  out[i + 3] = f2b(v.w);
}

// in[rows][cols] f32 -> out[cols][rows] bf16. grid (cols/32, rows/32), block (32,8)
__global__ void transpose_conv_kernel(const float* __restrict__ in, bf16* __restrict__ out,
                                      int rows, int cols) {
  __shared__ float tile[32][33];
  int bx = blockIdx.x * 32;
  int by = blockIdx.y * 32;
  int tx = threadIdx.x, ty = threadIdx.y;
#pragma unroll
  for (int i = 0; i < 32; i += 8)
    tile[ty + i][tx] = in[(size_t)(by + ty + i) * cols + bx + tx];
  __syncthreads();
#pragma unroll
  for (int i = 0; i < 32; i += 8)
    out[(size_t)(bx + ty + i) * rows + by + tx] = f2b(tile[tx][ty + i]);
}

// ---------------- 256x256 8-phase GEMM (round-3 pipelined; unchanged) ------

template <int KIND>  // 0=A0, 1=A1, 2=B0, 3=B1
static __device__ __forceinline__ void stage_half(const bf16* __restrict__ gsrc,
                                                  char* lds, int Kd, int tid) {
#pragma unroll
  for (int i = 0; i < 2; ++i) {
    int c = i * 512 + tid;
    int chunk;
    if (KIND < 2) chunk = c + ((c >> 9) << 9) + (KIND == 1 ? 512 : 0);
    else          chunk = c + ((c >> 8) << 8) + (KIND == 3 ? 256 : 0);
    int r  = chunk >> 3;
    int gc = (chunk & 7) ^ (r & 7);
    async_copy16(gsrc + (size_t)r * Kd + gc * 8, lds + (size_t)chunk * 16);
  }
}

#define RDA(DST, BUF, MH)                                         \
  _Pragma("unroll")                                               \
  for (int mt = 0; mt < 4; ++mt) {                                \
    DST[mt][0] = lda(BUF, MH, mt, 0);                             \
    DST[mt][1] = lda(BUF, MH, mt, 1);                             \
  }

#define RDB(DST, BUF, NH)                                         \
  _Pragma("unroll")                                               \
  for (int nt = 0; nt < 2; ++nt) {                                \
    DST[nt][0] = ldb(BUF, NH, nt, 0);                             \
    DST[nt][1] = ldb(BUF, NH, nt, 1);                             \
  }

#define MFMA_Q(AF, BF, MB, NB)                                    \
  _Pragma("unroll")                                               \
  for (int mt = 0; mt < 4; ++mt)                                  \
    _Pragma("unroll")                                             \
    for (int nt = 0; nt < 2; ++nt) {                              \
      acc[(MB) + mt][(NB) + nt] =                                 \
          mfma16(AF[mt][0], BF[nt][0], acc[(MB) + mt][(NB) + nt]);\
      acc[(MB) + mt][(NB) + nt] =                                 \
          mfma16(AF[mt][1], BF[nt][1], acc[(MB) + mt][(NB) + nt]);\
    }

#define GTILE(AC, BC, AN, BN, B0C, B0N, T)                        \
  {                                                               \
    bool s1 = (T) + 1 < NKT;                                      \
    bool s2 = (T) + 2 < NKT;                                      \
    const bf16* Ag1 = Ag + (size_t)((T) + 1) * 64;                \
    const bf16* Ag2 = Ag + (size_t)((T) + 2) * 64;                \
    const bf16* Bg2 = Bg + (size_t)((T) + 2) * 64;                \
    /* ---- P0: MFMA af0 x b0 ---- */                             \
    if (s1) stage_half<1>(Ag1, AN, Kd, tid);                      \
    RDB(b1, BC, 1);                                               \
    SBARRIER();                                                   \
    WAIT_LGKM(4);                                                 \
    PRIO1; MFMA_Q(af, B0C, 0, 0); PRIO0;                          \
    WAIT_VM(8);                                                   \
    SBARRIER();                                                   \
    /* ---- P1: MFMA af0 x b1; mid-issue af1 ---- */              \
    if (s2) stage_half<2>(Bg2, (char*)(BC), Kd, tid);             \
    SBARRIER();                                                   \
    WAIT_LGKM(0);                                                 \
    PRIO1; MFMA_Q(af, b1, 0, 2); PRIO0;                           \
    SCHEDBAR();                                                   \
    RDA(af, AC, 1);                                               \
    SBARRIER();                                                   \
    /* ---- P2: MFMA af1 x b1 ---- */                             \
    if (s2) stage_half<0>(Ag2, (char*)(AC), Kd, tid);             \
    SBARRIER();                                                   \
    WAIT_LGKM(0);                                                 \
    PRIO1; MFMA_Q(af, b1, 4, 2); PRIO0;                           \
    WAIT_VM(8);                                                   \
    SBARRIER();                                                   \
    /* ---- P3: MFMA af1 x b0; top: b0(t+1); mid: af0(t+1) ---- */\
    if (s2) stage_half<3>(Bg2, (char*)(BC), Kd, tid);             \
    if (s1) { RDB(B0N, BN, 0); }                                  \
    SBARRIER();                                                   \
    PRIO1; MFMA_Q(af, B0C, 4, 0); PRIO0;                          \
    SCHEDBAR();                                                   \
    if (s1) { RDA(af, AN, 0); }                                   \
    WAIT_VM(8);                                                   \
    SBARRIER();                                                   \
  }

template <bool OUT_F32>
__global__ __launch_bounds__(512, 2) void gemm256_kernel(
    const bf16* __restrict__ A, const bf16* __restrict__ BT,
    void* __restrict__ Cout, int M, int Nn, int Kd) {
  extern __shared__ char smem[];
  char* As0 = smem;
  char* As1 = smem + 32 * 1024;
  char* Bs0 = smem + 64 * 1024;
  char* Bs1 = smem + 96 * 1024;

  int tid  = threadIdx.x;
  int wave = tid >> 6, lane = tid & 63;
  int ml   = lane & 15, quad = lane >> 4;
  int wm   = wave >> 2, wn = wave & 3;

  int nbx = Nn >> 8;
  int nwg = gridDim.x;
  int id  = blockIdx.x;
  int swz = (id & 7) * (nwg >> 3) + (id >> 3);
  int bm  = (swz / nbx) << 8;
  int bn  = (swz % nbx) << 8;

  const bf16* Ag = A + (size_t)bm * Kd;
  const bf16* Bg = BT + (size_t)bn * Kd;

  facc acc[8][4];
#pragma unroll
  for (int i = 0; i < 8; ++i)
#pragma unroll
    for (int j = 0; j < 4; ++j)
#pragma unroll
      for (int r = 0; r < 4; ++r) acc[i][j][r] = 0.f;

  auto lda = [&](const char* buf, int mh, int mt, int kk) -> frag {
    int row = wm * 128 + mh * 64 + mt * 16 + ml;        // row&7 == ml&7
    int cs  = (kk * 4 + quad) ^ (ml & 7);
    return *(const frag*)(buf + ((size_t)row * 8 + cs) * 16);
  };
  auto ldb = [&](const char* buf, int nh, int nt, int kk) -> frag {
    int row = wn * 64 + nh * 32 + nt * 16 + ml;         // row&7 == ml&7
    int cs  = (kk * 4 + quad) ^ (ml & 7);
    return *(const frag*)(buf + ((size_t)row * 8 + cs) * 16);
  };

  int NKT = Kd >> 6;

  frag af[4][2], b0e[2][2], b0o[2][2], b1[2][2];

  stage_half<2>(Bg,      Bs0, Kd, tid);   // B0(0)
  stage_half<0>(Ag,      As0, Kd, tid);   // A0(0)
  stage_half<3>(Bg,      Bs0, Kd, tid);   // B1(0)
  stage_half<1>(Ag,      As0, Kd, tid);   // A1(0)
  stage_half<2>(Bg + 64, Bs1, Kd, tid);   // B0(1)
  stage_half<0>(Ag + 64, As1, Kd, tid);   // A0(1)
  stage_half<3>(Bg + 64, Bs1, Kd, tid);   // B1(1)
  WAIT_VM(10);
  SBARRIER();
  RDB(b0e, Bs0, 0);    // b0(0)
  SCHEDBAR();
  RDA(af, As0, 0);     // af0(0)
  WAIT_VM(8);
  SBARRIER();

  for (int kt = 0; kt < NKT; kt += 2) {
    GTILE(As0, Bs0, As1, Bs1, b0e, b0o, kt);
    GTILE(As1, Bs1, As0, Bs0, b0o, b0e, kt + 1);
  }

#pragma unroll
  for (int mi = 0; mi < 8; ++mi)
#pragma unroll
    for (int ni = 0; ni < 4; ++ni)
#pragma unroll
      for (int r = 0; r < 4; ++r) {
        size_t row = bm + wm * 128 + mi * 16 + quad * 4 + r;
        size_t col = bn + wn * 64 + ni * 16 + ml;
        float v = acc[mi][ni][r];
        if (OUT_F32) ((float*)Cout)[row * Nn + col] = v;
        else         ((bf16*)Cout)[row * Nn + col] = f2b(v);
      }
}

// ---------------- kv GEMM: BM=256 x BN=128, 256 blocks (full GPU) ----------
// 8 waves = 4M x 2N, per-wave 64x64 out (acc[4][4] = 64 regs). BK=64.
// LDS 96KB: A dbuf 2x32KB + B dbuf 2x16KB, same 16B-chunk XOR swizzle via
// pre-swizzled global source. 2 phases/K-tile, 16 MFMA each:
//   PA: rows mh0 (wave rows wm*64+0..31)  x all 64 cols
//   PB: rows mh1 (wave rows wm*64+32..63) x all 64 cols
// Stage halves (interleaved 32-row groups; A half = 2 loads, B half = 1):
//   A0 = rows {g*64+0..31}, A1 = rows {g*64+32..63}; B0/B1 likewise on 128.
// Region safety: A0/B0/B1 read at PA-top (lgkm'd in PA) -> restage in PB;
// A1 read at PB-top -> restage next PA (other buf). Counted vmcnt: loads
// in flight = [A0/B0/B1(t+1)]@PB(t-1) 4 + [A1(t+1)]@PA(t) 2 -> wait(6) at
// both phase ends in steady state; tails 2/0.

template <int KIND>  // 0=A0, 1=A1 (2 loads); 2=B0, 3=B1 (1 load)
static __device__ __forceinline__ void stage_kv(const bf16* __restrict__ gsrc,
                                                char* lds, int Kd, int tid) {
  if (KIND < 2) {
#pragma unroll
    for (int i = 0; i < 2; ++i) {
      int c = i * 512 + tid;
      int chunk = c + ((c >> 8) << 8) + (KIND == 1 ? 256 : 0);
      int r  = chunk >> 3;
      int gc = (chunk & 7) ^ (r & 7);
      async_copy16(gsrc + (size_t)r * Kd + gc * 8, lds + (size_t)chunk * 16);
    }
  } else {
    int c = tid;
    int chunk = c + ((c >> 8) << 8) + (KIND == 3 ? 256 : 0);
    int r  = chunk >> 3;
    int gc = (chunk & 7) ^ (r & 7);
    async_copy16(gsrc + (size_t)r * Kd + gc * 8, lds + (size_t)chunk * 16);
  }
}

__global__ __launch_bounds__(512, 2) void gemm_kv_kernel(
    const bf16* __restrict__ A, const bf16* __restrict__ BT,
    bf16* __restrict__ Cout, int M, int Nn, int Kd) {
  extern __shared__ char smem[];
  char* As0 = smem;                 // 32KB
  char* As1 = smem + 32 * 1024;     // 32KB
  char* Bs0 = smem + 64 * 1024;     // 16KB
  char* Bs1 = smem + 80 * 1024;     // 16KB

  int tid  = threadIdx.x;
  int wave = tid >> 6, lane = tid & 63;
  int ml   = lane & 15, quad = lane >> 4;
  int wm   = wave >> 1, wn = wave & 1;   // 4M x 2N

  int nbx = Nn >> 7;                // 128-wide n tiles
  int nwg = gridDim.x;
  int id  = blockIdx.x;
  int swz = (id & 7) * (nwg >> 3) + (id >> 3);
  int bm  = (swz / nbx) << 8;
  int bn  = (swz % nbx) << 7;

  const bf16* Ag = A + (size_t)bm * Kd;
  const bf16* Bg = BT + (size_t)bn * Kd;

  facc acc[4][4];
#pragma unroll
  for (int i = 0; i < 4; ++i)
#pragma unroll
    for (int j = 0; j < 4; ++j)
#pragma unroll
      for (int r = 0; r < 4; ++r) acc[i][j][r] = 0.f;

  auto lda = [&](const char* buf, int mh, int mt, int kk) -> frag {
    int row = wm * 64 + mh * 32 + mt * 16 + ml;         // row&7 == ml&7
    int cs  = (kk * 4 + quad) ^ (ml & 7);
    return *(const frag*)(buf + ((size_t)row * 8 + cs) * 16);
  };
  auto ldb = [&](const char* buf, int nt, int kk) -> frag {
    int row = wn * 64 + nt * 16 + ml;                   // row&7 == ml&7
    int cs  = (kk * 4 + quad) ^ (ml & 7);
    return *(const frag*)(buf + ((size_t)row * 8 + cs) * 16);
  };

  int NKT = Kd >> 6;

  frag af[2][2], bf[4][2];

  // prologue: A0/B0/B1(0) [4 loads], A1(0) [2], A0/B0/B1(1) [4]
  stage_kv<0>(Ag,      As0, Kd, tid);
  stage_kv<2>(Bg,      Bs0, Kd, tid);
  stage_kv<3>(Bg,      Bs0, Kd, tid);
  stage_kv<1>(Ag,      As0, Kd, tid);
  stage_kv<0>(Ag + 64, As1, Kd, tid);
  stage_kv<2>(Bg + 64, Bs1, Kd, tid);
  stage_kv<3>(Bg + 64, Bs1, Kd, tid);
  WAIT_VM(6);   // A0/B0/B1(0) landed
  SBARRIER();

  for (int kt = 0; kt < NKT; ++kt) {
    const char* Ac = (kt & 1) ? As1 : As0;
    const char* Bc = (kt & 1) ? Bs1 : Bs0;
    char* An = (kt & 1) ? As0 : As1;
    bool s1 = kt + 1 < NKT;
    bool s2 = kt + 2 < NKT;
    const bf16* Ag1 = Ag + (size_t)(kt + 1) * 64;
    const bf16* Ag2 = Ag + (size_t)(kt + 2) * 64;
    const bf16* Bg2 = Bg + (size_t)(kt + 2) * 64;

    // ---- PA: rows mh0 x all cols; stage A1(t+1) -> other buf
    if (s1) stage_kv<1>(Ag1, An, Kd, tid);
#pragma unroll
    for (int mt = 0; mt < 2; ++mt) {
      af[mt][0] = lda(Ac, 0, mt, 0);
      af[mt][1] = lda(Ac, 0, mt, 1);
    }
#pragma unroll
    for (int nt = 0; nt < 4; ++nt) {
      bf[nt][0] = ldb(Bc, nt, 0);
      bf[nt][1] = ldb(Bc, nt, 1);
    }
    SBARRIER();
    WAIT_LGKM(0);
    PRIO1;
#pragma unroll
    for (int mt = 0; mt < 2; ++mt)
#pragma unroll
      for (int nt = 0; nt < 4; ++nt) {
        acc[mt][nt] = mfma16(af[mt][0], bf[nt][0], acc[mt][nt]);
        acc[mt][nt] = mfma16(af[mt][1], bf[nt][1], acc[mt][nt]);
      }
    PRIO0;
    if (s1) { WAIT_VM(6); } else { WAIT_VM(0); }
    SBARRIER();

    // ---- PB: rows mh1 x all cols; stage A0/B0/B1(t+2) -> current buf
    if (s2) {
      stage_kv<0>(Ag2, (char*)Ac, Kd, tid);
      stage_kv<2>(Bg2, (char*)Bc, Kd, tid);
      stage_kv<3>(Bg2, (char*)Bc, Kd, tid);
    }
#pragma unroll
    for (int mt = 0; mt < 2; ++mt) {
      af[mt][0] = lda(Ac, 1, mt, 0);
      af[mt][1] = lda(Ac, 1, mt, 1);
    }
    SBARRIER();
    WAIT_LGKM(0);
    PRIO1;
#pragma unroll
    for (int mt = 0; mt < 2; ++mt)
#pragma unroll
      for (int nt = 0; nt < 4; ++nt) {
        acc[2 + mt][nt] = mfma16(af[mt][0], bf[nt][0], acc[2 + mt][nt]);
        acc[2 + mt][nt] = mfma16(af[mt][1], bf[nt][1], acc[2 + mt][nt]);
      }
    PRIO0;
    if (s1) {
      if (s2) { WAIT_VM(6); } else { WAIT_VM(2); }
      SBARRIER();
    }
  }

  // epilogue
#pragma unroll
  for (int mi = 0; mi < 4; ++mi)
#pragma unroll
    for (int ni = 0; ni < 4; ++ni)
#pragma unroll
      for (int r = 0; r < 4; ++r) {
        size_t row = bm + wm * 64 + (mi >> 1) * 32 + (mi & 1) * 16 + quad * 4 + r;
        size_t col = bn + wn * 64 + ni * 16 + ml;
        Cout[row * Nn + col] = f2b(acc[mi][ni][r]);
      }
}

// ---------------- RoPE (in place; q additionally prescaled by 1/sqrt(HD)) ----

__global__ void rope_kernel(bf16* __restrict__ qh, bf16* __restrict__ kvb,
                            const float* __restrict__ cosb, const float* __restrict__ sinb,
                            const int* __restrict__ positions) {
  const float qscale = 0.08838834764831843f;  // 1/sqrt(128), folded into q
  int idx   = blockIdx.x * blockDim.x + threadIdx.x;
  int token = idx / 2560;
  int p     = idx % 2560;
  int pos   = positions[token];
  bf16* base;
  int i;
  float sc;
  if (p < 2048) {  // q: 32 heads x 64 pairs
    int hh = p >> 6; i = p & 63;
    base = qh + (size_t)token * 4096 + hh * 128 + 2 * i;
    sc = qscale;
  } else {         // k: 8 heads x 64 pairs
    int pk = p - 2048;
    int hh = pk >> 6; i = pk & 63;
    base = kvb + (size_t)token * 2048 + hh * 128 + 2 * i;
    sc = 1.0f;
  }
  float c = cosb[pos * 64 + i] * sc, s = sinb[pos * 64 + i] * sc;
  float x1 = __bfloat162float(base[0]);
  float x2 = __bfloat162float(base[1]);
  base[0] = f2b(x1 * c - x2 * s);
  base[1] = f2b(x1 * s + x2 * c);
}

// ---------------- V transpose: kvb v-part [t][d] -> vt [b][kvh][d][t] -------

__global__ void vtrans_kernel(const bf16* __restrict__ kvb, bf16* __restrict__ vt) {
  __shared__ bf16 tile[32][33];
  int dt = blockIdx.x * 32;
  int tt = blockIdx.y * 32;
  int bk = blockIdx.z;
  int b = bk >> 3, kvh = bk & 7;
  const bf16* in = kvb + (size_t)(b * 1024) * 2048 + 1024 + kvh * 128;
  bf16* out = vt + (size_t)bk * 128 * 1024;
  int tx = threadIdx.x, ty = threadIdx.y;
#pragma unroll
  for (int i = 0; i < 32; i += 8)
    tile[ty + i][tx] = in[(size_t)(tt + ty + i) * 2048 + dt + tx];
  __syncthreads();
#pragma unroll
  for (int i = 0; i < 32; i += 8)
    out[(size_t)(dt + ty + i) * 1024 + tt + tx] = tile[tx][ty + i];
}

// ---------------- flash attention (GQA + q-subtile shared K/V tiles) --------
// (unchanged from round 2; see comments there)

__global__ __launch_bounds__(512, 4) void attn_kernel(
    const bf16* __restrict__ qh, const bf16* __restrict__ kvb,
    const bf16* __restrict__ vt, bf16* __restrict__ attn) {
  __shared__ alignas(16) bf16 Ks[64 * 128];   // 16KB
  __shared__ alignas(16) bf16 Vs[128 * 64];   // 16KB
  __shared__ alignas(16) bf16 Ps[8][16 * 84]; // 21504B

  int tid  = threadIdx.x;
  int wave = tid >> 6;
  int lane = tid & 63;
  int ml   = lane & 15, quad = lane >> 4;
  int wq   = wave >> 2;        // q-subtile 0/1
  int wh   = wave & 3;         // head within kv group

  int pr  = blockIdx.x;        // 0..15 (pair index)
  int kvh = blockIdx.y;        // 0..7
  int b   = blockIdx.z;        // 0..3
  int h   = kvh * 4 + wh;

  const bf16* kbptr = kvb + (size_t)(b * 1024) * 2048 + kvh * 128;
  const bf16* vbptr = vt + (size_t)((b * 8 + kvh) * 128) * 1024;
  bf16* Pw = &Ps[wave][0];

#pragma unroll
  for (int half = 0; half < 2; ++half) {
    int qtile = half ? pr : (31 - pr);   // big tile first
    int q0 = qtile * 32 + wq * 16;

    // Q fragments: rows q0+ml, head h (already 1/sqrt(HD) scaled)
    frag qf[4];
    const bf16* qrow = qh + (size_t)(b * 1024 + q0 + ml) * 4096 + h * 128;
#pragma unroll
    for (int s = 0; s < 4; ++s) qf[s] = *(const frag*)(qrow + s * 32 + quad * 8);

    facc o[8];
#pragma unroll
    for (int db = 0; db < 8; ++db)
#pragma unroll
      for (int r = 0; r < 4; ++r) o[db][r] = 0.f;
    float m_i[4], l_i[4];
#pragma unroll
    for (int r = 0; r < 4; ++r) { m_i[r] = -1e30f; l_i[r] = 0.f; }

    int nkb = (qtile >> 1) + 1;  // K tiles of 64 covering 0..qtile*32+31

    for (int kb = 0; kb < nkb; ++kb) {
      int kbase = kb * 64;
      __syncthreads();  // prev LDS reads (and prev half's PV) done before restage
      // stage K tile: 1024 chunks of 16B over 512 threads
#pragma unroll
      for (int i = 0; i < 2; ++i) {
        int c = i * 512 + tid;
        int row = c >> 4, cs = c & 15;
        int gc = cs ^ (row & 7);
        async_copy16(kbptr + (size_t)(kbase + row) * 2048 + gc * 8, (char*)Ks + c * 16);
      }
      // stage V tile: [d][64 t], 8 chunks/row
#pragma unroll
      for (int i = 0; i < 2; ++i) {
        int c = i * 512 + tid;
        int d = c >> 3, cs = c & 7;
        int gc = cs ^ (d & 7);
        async_copy16(vbptr + (size_t)d * 1024 + kbase + gc * 8, (char*)Vs + c * 16);
      }
      __syncthreads();  // drains vmcnt -> tiles ready

      // QK^T: S[16q][64k] as 4 k-tiles of 16
      facc sc[4];
#pragma unroll
      for (int kt = 0; kt < 4; ++kt)
#pragma unroll
        for (int r = 0; r < 4; ++r) sc[kt][r] = 0.f;
#pragma unroll
      for (int s = 0; s < 4; ++s)
#pragma unroll
        for (int kt = 0; kt < 4; ++kt) {
          int row = kt * 16 + ml;
          int cs = ((s * 4 + quad) ^ (ml & 7));  // row&7 == ml&7
          frag kf = *(const frag*)&Ks[row * 128 + cs * 8];
          sc[kt] = __builtin_amdgcn_mfma_f32_16x16x32_bf16(qf[s], kf, sc[kt], 0, 0, 0);
        }

      // online softmax; causal mask
#pragma unroll
      for (int r = 0; r < 4; ++r) {
        int qp = q0 + quad * 4 + r;
        float v[4];
        float mx = -1e30f;
#pragma unroll
        for (int kt = 0; kt < 4; ++kt) {
          float s = sc[kt][r];
          if (qp < kbase + kt * 16 + ml) s = -1e30f;
          v[kt] = s;
          mx = fmaxf(mx, s);
        }
        mx = fmaxf(mx, __shfl_xor(mx, 1));
        mx = fmaxf(mx, __shfl_xor(mx, 2));
        mx = fmaxf(mx, __shfl_xor(mx, 4));
        mx = fmaxf(mx, __shfl_xor(mx, 8));
        float mnew  = fmaxf(m_i[r], mx);
        float alpha = __expf(m_i[r] - mnew);
        m_i[r] = mnew;
        float ps = 0.f;
#pragma unroll
        for (int kt = 0; kt < 4; ++kt) {
          float p = __expf(v[kt] - mnew);
          ps += p;
          Pw[(quad * 4 + r) * 84 + kt * 16 + ml] = f2b(p);
        }
        ps += __shfl_xor(ps, 1);
        ps += __shfl_xor(ps, 2);
        ps += __shfl_xor(ps, 4);
        ps += __shfl_xor(ps, 8);
        l_i[r] = l_i[r] * alpha + ps;
#pragma unroll
        for (int db = 0; db < 8; ++db) o[db][r] *= alpha;
      }
      __syncthreads();  // P visible (per-wave buffer; barrier for safe lgkm order)

      // PV: P[16q][64k] x V[64k][128d]
#pragma unroll
      for (int j = 0; j < 2; ++j) {
        frag pf = *(const frag*)&Pw[ml * 84 + j * 32 + quad * 8];
#pragma unroll
        for (int db = 0; db < 8; ++db) {
          int d = db * 16 + ml;
          int cs = ((j * 4 + quad) ^ (ml & 7));  // d&7 == ml&7
          frag vf = *(const frag*)&Vs[d * 64 + cs * 8];
          o[db] = __builtin_amdgcn_mfma_f32_16x16x32_bf16(pf, vf, o[db], 0, 0, 0);
        }
      }
    }

    bf16* arow = attn + (size_t)(b * 1024 + q0) * 4096 + h * 128;
#pragma unroll
    for (int db = 0; db < 8; ++db)
#pragma unroll
      for (int r = 0; r < 4; ++r) {
        float v = o[db][r] / l_i[r];
        arow[(size_t)(quad * 4 + r) * 4096 + db * 16 + ml] = f2b(v);
      }
  }
}

// ---------------- launch ----------------

extern "C" void kernel_launch(void* const* d_in, const int* in_sizes, int n_in,
                              void* d_out, int out_size, void* d_ws, size_t ws_size,
                              hipStream_t stream) {
  const float* x        = (const float*)d_in[0];
  const float* w_q      = (const float*)d_in[1];
  const float* w_kv     = (const float*)d_in[2];
  const float* w_o      = (const float*)d_in[3];
  const float* rope_cos = (const float*)d_in[6];
  const float* rope_sin = (const float*)d_in[7];
  const int*   positions = (const int*)d_in[8];
  float* out = (float*)d_out;

  char* ws = (char*)d_ws;
  const size_t MB = 1024 * 1024;
  bf16* xb    = (bf16*)(ws + 0);
  bf16* wqT   = (bf16*)(ws + 32 * MB);
  bf16* wkvT  = (bf16*)(ws + 64 * MB);
  bf16* woT   = (bf16*)(ws + 80 * MB);
  bf16* qh    = (bf16*)(ws + 112 * MB);
  bf16* kvb   = (bf16*)(ws + 144 * MB);
  bf16* vt    = (bf16*)(ws + 160 * MB);
  bf16* attnb = xb;  // xb dead after kv GEMM

  static bool s_attr = false;
  if (!s_attr) {
    hipFuncSetAttribute(reinterpret_cast<const void*>(gemm256_kernel<false>),
                        hipFuncAttributeMaxDynamicSharedMemorySize, 131072);
    hipFuncSetAttribute(reinterpret_cast<const void*>(gemm256_kernel<true>),
                        hipFuncAttributeMaxDynamicSharedMemorySize, 131072);
    hipFuncSetAttribute(reinterpret_cast<const void*>(gemm_kv_kernel),
                        hipFuncAttributeMaxDynamicSharedMemorySize, 98304);
    s_attr = true;
  }

  convert_x_kernel<<<16384, 256, 0, stream>>>(x, xb);
  transpose_conv_kernel<<<dim3(128, 128), dim3(32, 8), 0, stream>>>(w_q, wqT, 4096, 4096);
  transpose_conv_kernel<<<dim3(64, 128),  dim3(32, 8), 0, stream>>>(w_kv, wkvT, 4096, 2048);
  transpose_conv_kernel<<<dim3(128, 128), dim3(32, 8), 0, stream>>>(w_o, woT, 4096, 4096);

  gemm256_kernel<false><<<dim3(256), 512, 131072, stream>>>(xb, wqT, qh, 4096, 4096, 4096);
  gemm_kv_kernel<<<dim3(256), 512, 98304, stream>>>(xb, wkvT, kvb, 4096, 2048, 4096);

  rope_kernel<<<40960, 256, 0, stream>>>(qh, kvb, rope_cos, rope_sin, positions);
  vtrans_kernel<<<dim3(4, 32, 32), dim3(32, 8), 0, stream>>>(kvb, vt);

  attn_kernel<<<dim3(16, 8, 4), 512, 0, stream>>>(qh, kvb, vt, attnb);

  gemm256_kernel<true><<<dim3(256), 512, 131072, stream>>>(attnb, woT, out, 4096, 4096, 4096);
}